// Round 1
// baseline (6388.348 us; speedup 1.0000x reference)
//
#include <hip/hip_runtime.h>
#include <math.h>

#define D 256
#define S 4096
#define H 8
#define DH 32
#define DM 1024
#define NTOK 8192   // B*S

// ---------------- LayerNorm: one block per token row ----------------
__global__ void ln_kernel(const float* __restrict__ x, const float* __restrict__ g,
                          const float* __restrict__ b, float* __restrict__ out) {
    __shared__ float red[8];
    int row = blockIdx.x;
    int tid = threadIdx.x;
    float v = x[row * D + tid];
    float s = v, s2 = v * v;
    #pragma unroll
    for (int off = 32; off > 0; off >>= 1) {
        s  += __shfl_xor(s, off, 64);
        s2 += __shfl_xor(s2, off, 64);
    }
    int wave = tid >> 6;
    if ((tid & 63) == 0) { red[wave] = s; red[wave + 4] = s2; }
    __syncthreads();
    float sum   = red[0] + red[1] + red[2] + red[3];
    float sumsq = red[4] + red[5] + red[6] + red[7];
    float mu  = sum * (1.0f / D);
    float var = sumsq * (1.0f / D) - mu * mu;
    float rs  = rsqrtf(var + 1e-5f);
    out[row * D + tid] = (v - mu) * rs * g[tid] + b[tid];
}

// ---------------- QKV projection + RoPE fused ----------------
__global__ void qkv_kernel(const float* __restrict__ xn,
                           const float* __restrict__ Wq,
                           const float* __restrict__ Wk,
                           const float* __restrict__ Wv,
                           float* __restrict__ qo, float* __restrict__ ko,
                           float* __restrict__ vo) {
    __shared__ float xs[D];
    int row = blockIdx.x;
    int tid = threadIdx.x;
    xs[tid] = xn[row * D + tid];
    __syncthreads();
    const float* wq = Wq + tid * D;
    const float* wk = Wk + tid * D;
    const float* wv = Wv + tid * D;
    float aq = 0.f, ak = 0.f, av = 0.f;
    for (int i = 0; i < D; ++i) {
        float xv = xs[i];
        aq = fmaf(xv, wq[i], aq);
        ak = fmaf(xv, wk[i], ak);
        av = fmaf(xv, wv[i], av);
    }
    // RoPE (interleaved pairs) on q,k
    int spos = row & (S - 1);
    int d    = tid & (DH - 1);
    int pi   = d >> 1;
    float inv_freq = powf(10000.0f, -(float)(2 * pi) / (float)DH);
    float fr = (float)spos * inv_freq;
    float cs = cosf(fr), sn = sinf(fr);
    float pq = __shfl_xor(aq, 1, 64);  // partner within pair
    float pk = __shfl_xor(ak, 1, 64);
    float rq = (d & 1) ? pq : -pq;
    float rk = (d & 1) ? pk : -pk;
    qo[row * D + tid] = aq * cs + rq * sn;
    ko[row * D + tid] = ak * cs + rk * sn;
    vo[row * D + tid] = av;
}

// ---------------- Flash attention ----------------
// block = 256 threads: (r = tid/32) query row in 8-row tile, (c = tid%32) lane.
// grid = B*H*(S/8) = 8192 blocks.
__global__ void attn_kernel(const float* __restrict__ q, const float* __restrict__ k,
                            const float* __restrict__ v, float* __restrict__ out) {
    __shared__ float Qs[8][DH + 1];
    __shared__ float Ks[32][DH + 1];
    __shared__ float Vs[32][DH + 1];
    int tid = threadIdx.x;
    int r = tid >> 5;
    int c = tid & 31;
    int qt = blockIdx.x & 511;      // 512 q-tiles of 8 rows
    int bh = blockIdx.x >> 9;
    int b  = bh >> 3;
    int h  = bh & 7;
    int qrow = qt * 8 + r;
    long base = (long)(b * S) * D + h * DH;
    Qs[r][c] = q[base + (long)qrow * D + c];
    float m = -INFINITY, l = 0.f, o = 0.f;
    const float rscale = 0.17677669529663687f;  // 1/sqrt(32)
    for (int kt = 0; kt < S / 32; ++kt) {
        __syncthreads();   // prior iteration's Vs reads done
        #pragma unroll
        for (int it = 0; it < 4; ++it) {
            int e = it * 256 + tid;
            int j = e >> 5, dd = e & 31;
            long addr = base + (long)(kt * 32 + j) * D + dd;
            Ks[j][dd] = k[addr];
            Vs[j][dd] = v[addr];
        }
        __syncthreads();
        float sc = 0.f;
        #pragma unroll
        for (int d2 = 0; d2 < DH; ++d2) sc = fmaf(Qs[r][d2], Ks[c][d2], sc);
        sc *= rscale;
        float tm = sc;
        #pragma unroll
        for (int off = 16; off > 0; off >>= 1) tm = fmaxf(tm, __shfl_xor(tm, off, 32));
        float mn = fmaxf(m, tm);
        float alpha = expf(m - mn);          // first iter: exp(-inf)=0
        float p = expf(sc - mn);
        float ps = p;
        #pragma unroll
        for (int off = 16; off > 0; off >>= 1) ps += __shfl_xor(ps, off, 32);
        l = l * alpha + ps;
        o *= alpha;
        m = mn;
        #pragma unroll
        for (int j2 = 0; j2 < 32; ++j2) {
            o = fmaf(__shfl(p, j2, 32), Vs[j2][c], o);
        }
    }
    out[base + (long)qrow * D + c] = o / l;
}

// ---------------- Wo projection + residual ----------------
__global__ void wo_res_kernel(const float* __restrict__ attn, const float* __restrict__ Wo,
                              const float* __restrict__ x, float* __restrict__ mlp_in) {
    __shared__ float as[D];
    int row = blockIdx.x, tid = threadIdx.x;
    as[tid] = attn[row * D + tid];
    __syncthreads();
    const float* w = Wo + tid * D;
    float acc = 0.f;
    for (int i = 0; i < D; ++i) acc = fmaf(as[i], w[i], acc);
    mlp_in[row * D + tid] = acc + x[row * D + tid];
}

// ---------------- MLP layer 1 + exact GELU ----------------
__global__ void mlp1_kernel(const float* __restrict__ yn, const float* __restrict__ W2,
                            const float* __restrict__ b2, float* __restrict__ hbuf) {
    __shared__ float ys[D];
    int row = blockIdx.x, tid = threadIdx.x;
    ys[tid] = yn[row * D + tid];
    __syncthreads();
    #pragma unroll
    for (int mi = 0; mi < 4; ++mi) {
        int mcol = mi * 256 + tid;
        const float* w = W2 + mcol * D;
        float acc = b2[mcol];
        for (int i = 0; i < D; ++i) acc = fmaf(ys[i], w[i], acc);
        float gel = 0.5f * acc * (1.0f + erff(acc * 0.70710678118654752f));
        hbuf[(long)row * DM + mcol] = gel;
    }
}

// ---------------- MLP layer 2 + bias + residual ----------------
__global__ void mlp2_kernel(const float* __restrict__ hbuf, const float* __restrict__ W3,
                            const float* __restrict__ b3, const float* __restrict__ mlp_in,
                            float* __restrict__ out) {
    __shared__ float hs[DM];
    int row = blockIdx.x, tid = threadIdx.x;
    #pragma unroll
    for (int i = 0; i < 4; ++i) hs[i * 256 + tid] = hbuf[(long)row * DM + i * 256 + tid];
    __syncthreads();
    const float* w = W3 + tid * DM;
    float acc = b3[tid];
    for (int i = 0; i < DM; ++i) acc = fmaf(hs[i], w[i], acc);
    out[row * D + tid] = acc + mlp_in[row * D + tid];
}

extern "C" void kernel_launch(void* const* d_in, const int* in_sizes, int n_in,
                              void* d_out, int out_size, void* d_ws, size_t ws_size,
                              hipStream_t stream) {
    const float* x     = (const float*)d_in[0];
    const float* Wq    = (const float*)d_in[1];
    const float* Wk    = (const float*)d_in[2];
    const float* Wv    = (const float*)d_in[3];
    const float* Wo    = (const float*)d_in[4];
    const float* ln1_g = (const float*)d_in[5];
    const float* ln1_b = (const float*)d_in[6];
    const float* ln2_g = (const float*)d_in[7];
    const float* ln2_b = (const float*)d_in[8];
    const float* W2    = (const float*)d_in[9];
    const float* b2    = (const float*)d_in[10];
    const float* W3    = (const float*)d_in[11];
    const float* b3    = (const float*)d_in[12];
    float* out = (float*)d_out;
    float* ws  = (float*)d_ws;

    const size_t CH = 2097152;     // NTOK * D
    float* xn  = ws;               // [0, 2M)   — later reused as yn
    float* qb  = ws + CH;          // [2M, 4M)
    float* kb  = ws + 2 * CH;      // [4M, 6M)
    float* vb  = ws + 3 * CH;      // [6M, 8M)
    float* ab  = ws + 4 * CH;      // [8M, 10M)
    float* mlp = ws + 5 * CH;      // [10M, 12M) — persists to the end
    float* hb  = qb;               // reuse [2M, 10M) = 8M floats for MLP hidden
    float* yn  = xn;               // reuse after QKV consumed xn

    ln_kernel  <<<NTOK, 256, 0, stream>>>(x, ln1_g, ln1_b, xn);
    qkv_kernel <<<NTOK, 256, 0, stream>>>(xn, Wq, Wk, Wv, qb, kb, vb);
    attn_kernel<<<8192, 256, 0, stream>>>(qb, kb, vb, ab);
    wo_res_kernel<<<NTOK, 256, 0, stream>>>(ab, Wo, x, mlp);
    ln_kernel  <<<NTOK, 256, 0, stream>>>(mlp, ln2_g, ln2_b, yn);
    mlp1_kernel<<<NTOK, 256, 0, stream>>>(yn, W2, b2, hb);
    mlp2_kernel<<<NTOK, 256, 0, stream>>>(hb, W3, b3, mlp, out);
}

// Round 2
// 454.715 us; speedup vs baseline: 14.0491x; 14.0491x over previous
//
#include <hip/hip_runtime.h>
#include <math.h>

#define D 256
#define S 4096
#define H 8
#define DH 32
#define DM 1024
#define NTOK 8192   // B*S

typedef __attribute__((ext_vector_type(8))) short short8;
typedef __attribute__((ext_vector_type(4))) float f32x4;

__device__ inline float bf2f(unsigned short u) {
    union { unsigned u; float f; } v; v.u = ((unsigned)u) << 16; return v.f;
}
__device__ inline unsigned short f2bf(float f) {
    union { float f; unsigned u; } v; v.f = f;
    unsigned r = v.u + 0x7fffu + ((v.u >> 16) & 1u);
    return (unsigned short)(r >> 16);
}
__device__ inline void gload16(const void* g, void* l) {
    __builtin_amdgcn_global_load_lds((const __attribute__((address_space(1))) void*)g,
                                     (__attribute__((address_space(3))) void*)l, 16, 0, 0);
}

// ---------------- fp32 -> bf16 weight conversion ----------------
__global__ void conv_kernel(const float* __restrict__ src, unsigned short* __restrict__ dst, int n) {
    int i = blockIdx.x * 256 + threadIdx.x;
    if (i < n) dst[i] = f2bf(src[i]);
}

// ---------------- LayerNorm: fp32 in, bf16 out ----------------
__global__ void ln_kernel(const float* __restrict__ x, const float* __restrict__ g,
                          const float* __restrict__ b, unsigned short* __restrict__ out) {
    __shared__ float red[8];
    int row = blockIdx.x;
    int tid = threadIdx.x;
    float v = x[(size_t)row * D + tid];
    float s = v, s2 = v * v;
    #pragma unroll
    for (int off = 32; off > 0; off >>= 1) {
        s  += __shfl_xor(s, off, 64);
        s2 += __shfl_xor(s2, off, 64);
    }
    int wave = tid >> 6;
    if ((tid & 63) == 0) { red[wave] = s; red[wave + 4] = s2; }
    __syncthreads();
    float sum   = red[0] + red[1] + red[2] + red[3];
    float sumsq = red[4] + red[5] + red[6] + red[7];
    float mu  = sum * (1.0f / D);
    float var = sumsq * (1.0f / D) - mu * mu;
    float rs  = rsqrtf(var + 1e-5f);
    out[(size_t)row * D + tid] = f2bf((v - mu) * rs * g[tid] + b[tid]);
}

// ---------------- bf16 MFMA GEMM: C[M][N] = A[M][K] * Bw[N][K]^T ----------------
// modes: 0 = store bf16 raw; 1 = fp32 store acc+res; 2 = bf16 store gelu(acc+bias);
//        3 = fp32 store acc+bias+res
__global__ __launch_bounds__(256) void gemm_bt(const unsigned short* __restrict__ A,
        const unsigned short* __restrict__ Bw, void* __restrict__ outp,
        const float* __restrict__ bias, const float* __restrict__ res,
        int N, int K, int mode) {
    __shared__ unsigned short As[128 * 32];
    __shared__ unsigned short Bs[128 * 32];
    int tid = threadIdx.x;
    int w = tid >> 6, l = tid & 63;
    int lm = l & 15, lg = l >> 4;
    int wm = (w >> 1) * 64, wn = (w & 1) * 64;
    int bm = blockIdx.x * 128, bn = blockIdx.y * 128;
    int sr = l >> 2, sk = (l & 3) * 8;
    const unsigned short* Ag = A + (size_t)bm * K;
    const unsigned short* Bg = Bw + (size_t)bn * K;
    f32x4 acc[4][4] = {};

    for (int k0 = 0; k0 < K; k0 += 32) {
        __syncthreads();
        #pragma unroll
        for (int r = 0; r < 2; ++r) {
            int seg = r * 4 + w;
            gload16(Ag + (size_t)(seg * 16 + sr) * K + k0 + sk, &As[seg * 512]);
            gload16(Bg + (size_t)(seg * 16 + sr) * K + k0 + sk, &Bs[seg * 512]);
        }
        __syncthreads();
        short8 af[4], bf[4];
        #pragma unroll
        for (int i = 0; i < 4; ++i) af[i] = *(const short8*)&As[(wm + i * 16 + lm) * 32 + lg * 8];
        #pragma unroll
        for (int i = 0; i < 4; ++i) bf[i] = *(const short8*)&Bs[(wn + i * 16 + lm) * 32 + lg * 8];
        #pragma unroll
        for (int mi = 0; mi < 4; ++mi)
            #pragma unroll
            for (int ni = 0; ni < 4; ++ni)
                acc[mi][ni] = __builtin_amdgcn_mfma_f32_16x16x32_bf16(af[mi], bf[ni], acc[mi][ni], 0, 0, 0);
    }
    #pragma unroll
    for (int mi = 0; mi < 4; ++mi) {
        #pragma unroll
        for (int ni = 0; ni < 4; ++ni) {
            int ng = bn + wn + ni * 16 + lm;
            #pragma unroll
            for (int r2 = 0; r2 < 4; ++r2) {
                int mg = bm + wm + mi * 16 + lg * 4 + r2;
                float v = acc[mi][ni][r2];
                size_t idx = (size_t)mg * N + ng;
                if (mode == 0) {
                    ((unsigned short*)outp)[idx] = f2bf(v);
                } else if (mode == 1) {
                    ((float*)outp)[idx] = v + res[idx];
                } else if (mode == 2) {
                    float t = v + bias[ng];
                    ((unsigned short*)outp)[idx] = f2bf(0.5f * t * (1.0f + erff(t * 0.70710678118654752f)));
                } else {
                    ((float*)outp)[idx] = v + bias[ng] + res[idx];
                }
            }
        }
    }
}

// ---------------- RoPE on Q,K from the fused QKV output ----------------
__global__ void rope_kernel(const unsigned short* __restrict__ Cq,
                            unsigned short* __restrict__ qo, unsigned short* __restrict__ ko) {
    int row = blockIdx.x, t = threadIdx.x;
    float qv = bf2f(Cq[(size_t)row * 768 + t]);
    float kv = bf2f(Cq[(size_t)row * 768 + 256 + t]);
    int spos = row & (S - 1);
    int d = t & 31, pi = d >> 1;
    float inv_freq = powf(10000.0f, -(float)(2 * pi) / (float)DH);
    float fr = (float)spos * inv_freq;
    float cs = cosf(fr), sn = sinf(fr);
    float pq = __shfl_xor(qv, 1, 64);
    float pk = __shfl_xor(kv, 1, 64);
    float rq = (d & 1) ? pq : -pq;
    float rk = (d & 1) ? pk : -pk;
    qo[(size_t)row * D + t] = f2bf(qv * cs + rq * sn);
    ko[(size_t)row * D + t] = f2bf(kv * cs + rk * sn);
}

// ---------------- V transpose: Cq v-part -> vt[B][H][DH][S] ----------------
__global__ void vtrans_kernel(const unsigned short* __restrict__ Cq, unsigned short* __restrict__ vt) {
    __shared__ unsigned short Vs[32][72];
    int t = threadIdx.x;
    int sc = blockIdx.x & 63, bh = blockIdx.x >> 6;
    int b = bh >> 3, h = bh & 7;
    int s0 = sc * 64;
    int sl = t >> 2, g = t & 3;
    const unsigned short* src = Cq + (size_t)(b * S + s0 + sl) * 768 + 512 + h * 32 + g * 8;
    short8 u = *(const short8*)src;
    #pragma unroll
    for (int j = 0; j < 8; ++j) Vs[g * 8 + j][sl] = (unsigned short)u[j];
    __syncthreads();
    int dh = t >> 3, c = t & 7;
    short8 vv = *(const short8*)&Vs[dh][c * 8];
    *(short8*)(vt + ((size_t)(bh * 32 + dh)) * S + s0 + c * 8) = vv;
}

// ---------------- MFMA flash attention ----------------
// block = 256 threads = 4 waves; wave handles 16 q rows; block = 64 q rows of one (b,h).
// grid = B*H*(S/64) = 1024.
__global__ __launch_bounds__(256) void attn_kernel(const unsigned short* __restrict__ q,
        const unsigned short* __restrict__ k, const unsigned short* __restrict__ vt,
        unsigned short* __restrict__ out) {
    __shared__ unsigned short Plds[4][16][32];
    int tid = threadIdx.x;
    int w = tid >> 6, l = tid & 63;
    int lm = l & 15, lg = l >> 4;
    int qt = blockIdx.x & 63;
    int bh = blockIdx.x >> 6;
    int b = bh >> 3, h = bh & 7;
    int q0 = qt * 64 + w * 16;

    // Q fragment (acts as B operand of S^T = K * Q^T): Q[q0+lm][lg*8 .. +7]
    const short8 qf = *(const short8*)(q + ((size_t)(b * S + q0 + lm)) * D + h * DH + lg * 8);
    const unsigned short* kb = k + ((size_t)(b * S)) * D + h * DH + lg * 8;
    const unsigned short* vb = vt + ((size_t)bh * DH) * S;

    f32x4 o0 = {0.f, 0.f, 0.f, 0.f}, o1 = {0.f, 0.f, 0.f, 0.f};
    float m = -INFINITY, la = 0.f;
    const float rs = 0.17677669529663687f;  // 1/sqrt(32)

    for (int k0 = 0; k0 < S; k0 += 32) {
        short8 kf0 = *(const short8*)(kb + ((size_t)(k0 + lm)) * D);
        short8 kf1 = *(const short8*)(kb + ((size_t)(k0 + 16 + lm)) * D);
        f32x4 z = {0.f, 0.f, 0.f, 0.f};
        f32x4 s0 = __builtin_amdgcn_mfma_f32_16x16x32_bf16(kf0, qf, z, 0, 0, 0);
        f32x4 s1 = __builtin_amdgcn_mfma_f32_16x16x32_bf16(kf1, qf, z, 0, 0, 0);
        // S^T tile: lane holds keys (lg*4+r [+16]) for q column lm
        float v0[4], v1[4];
        float xm = -INFINITY;
        #pragma unroll
        for (int i = 0; i < 4; ++i) {
            v0[i] = s0[i] * rs; v1[i] = s1[i] * rs;
            xm = fmaxf(xm, fmaxf(v0[i], v1[i]));
        }
        xm = fmaxf(xm, __shfl_xor(xm, 16, 64));
        xm = fmaxf(xm, __shfl_xor(xm, 32, 64));
        float mn = fmaxf(m, xm);
        float alpha = __expf(m - mn);   // first iter: exp(-inf) = 0
        float ps = 0.f;
        unsigned short p0[4], p1[4];
        #pragma unroll
        for (int i = 0; i < 4; ++i) {
            float e0 = __expf(v0[i] - mn), e1 = __expf(v1[i] - mn);
            ps += e0 + e1;
            p0[i] = f2bf(e0); p1[i] = f2bf(e1);
        }
        ps += __shfl_xor(ps, 16, 64);
        ps += __shfl_xor(ps, 32, 64);
        la = la * alpha + ps;
        #pragma unroll
        for (int i = 0; i < 4; ++i) { o0[i] *= alpha; o1[i] *= alpha; }
        m = mn;
        // P round-trip through per-wave LDS: store [q][key], read back as B operand
        *(ushort4*)&Plds[w][lm][lg * 4]      = make_ushort4(p0[0], p0[1], p0[2], p0[3]);
        *(ushort4*)&Plds[w][lm][16 + lg * 4] = make_ushort4(p1[0], p1[1], p1[2], p1[3]);
        short8 pf = *(const short8*)&Plds[w][lm][lg * 8];
        short8 va0 = *(const short8*)(vb + ((size_t)lm) * S + k0 + lg * 8);
        short8 va1 = *(const short8*)(vb + ((size_t)(16 + lm)) * S + k0 + lg * 8);
        o0 = __builtin_amdgcn_mfma_f32_16x16x32_bf16(va0, pf, o0, 0, 0, 0);
        o1 = __builtin_amdgcn_mfma_f32_16x16x32_bf16(va1, pf, o1, 0, 0, 0);
    }
    float inv = 1.0f / la;
    ushort4 r0, r1;
    r0.x = f2bf(o0[0] * inv); r0.y = f2bf(o0[1] * inv);
    r0.z = f2bf(o0[2] * inv); r0.w = f2bf(o0[3] * inv);
    r1.x = f2bf(o1[0] * inv); r1.y = f2bf(o1[1] * inv);
    r1.z = f2bf(o1[2] * inv); r1.w = f2bf(o1[3] * inv);
    unsigned short* ob = out + ((size_t)(b * S + q0 + lm)) * D + h * DH;
    *(ushort4*)(ob + lg * 4)      = r0;
    *(ushort4*)(ob + 16 + lg * 4) = r1;
}

extern "C" void kernel_launch(void* const* d_in, const int* in_sizes, int n_in,
                              void* d_out, int out_size, void* d_ws, size_t ws_size,
                              hipStream_t stream) {
    const float* x     = (const float*)d_in[0];
    const float* Wq    = (const float*)d_in[1];
    const float* Wk    = (const float*)d_in[2];
    const float* Wv    = (const float*)d_in[3];
    const float* Wo    = (const float*)d_in[4];
    const float* ln1_g = (const float*)d_in[5];
    const float* ln1_b = (const float*)d_in[6];
    const float* ln2_g = (const float*)d_in[7];
    const float* ln2_b = (const float*)d_in[8];
    const float* W2    = (const float*)d_in[9];
    const float* b2    = (const float*)d_in[10];
    const float* W3    = (const float*)d_in[11];
    const float* b3    = (const float*)d_in[12];

    char* w8 = (char*)d_ws;
    unsigned short* wqkv = (unsigned short*)(w8);             // 196608 elem
    unsigned short* wo_b = (unsigned short*)(w8 + 393216);    // 65536
    unsigned short* w2_b = (unsigned short*)(w8 + 524288);    // 262144
    unsigned short* w3_b = (unsigned short*)(w8 + 1048576);   // 262144
    unsigned short* xn   = (unsigned short*)(w8 + 1572864);   // 2M elem (reused as yn)
    unsigned short* qb   = (unsigned short*)(w8 + 5767168);   // 2M
    unsigned short* kbuf = (unsigned short*)(w8 + 9961472);   // 2M
    unsigned short* vtb  = (unsigned short*)(w8 + 14155776);  // 2M
    unsigned short* ab   = (unsigned short*)(w8 + 18350080);  // 2M
    float*          mlpin= (float*)(w8 + 22544384);           // 2M fp32 = 8MB
    unsigned short* Cq   = (unsigned short*)(w8 + 30932992);  // 6.29M elem (QKV out)
    unsigned short* hb   = Cq;                                // reuse for MLP hidden (8.39M elem)
    unsigned short* yn   = xn;

    conv_kernel<<<256, 256, 0, stream>>>(Wq, wqkv, 65536);
    conv_kernel<<<256, 256, 0, stream>>>(Wk, wqkv + 65536, 65536);
    conv_kernel<<<256, 256, 0, stream>>>(Wv, wqkv + 131072, 65536);
    conv_kernel<<<256, 256, 0, stream>>>(Wo, wo_b, 65536);
    conv_kernel<<<1024, 256, 0, stream>>>(W2, w2_b, 262144);
    conv_kernel<<<1024, 256, 0, stream>>>(W3, w3_b, 262144);

    ln_kernel<<<NTOK, 256, 0, stream>>>(x, ln1_g, ln1_b, xn);
    gemm_bt<<<dim3(64, 6), 256, 0, stream>>>(xn, wqkv, Cq, nullptr, nullptr, 768, 256, 0);
    rope_kernel<<<NTOK, 256, 0, stream>>>(Cq, qb, kbuf);
    vtrans_kernel<<<1024, 256, 0, stream>>>(Cq, vtb);
    attn_kernel<<<1024, 256, 0, stream>>>(qb, kbuf, vtb, ab);
    gemm_bt<<<dim3(64, 2), 256, 0, stream>>>(ab, wo_b, mlpin, nullptr, x, 256, 256, 1);
    ln_kernel<<<NTOK, 256, 0, stream>>>(mlpin, ln2_g, ln2_b, yn);
    gemm_bt<<<dim3(64, 8), 256, 0, stream>>>(yn, w2_b, hb, b2, nullptr, 1024, 256, 2);
    gemm_bt<<<dim3(64, 2), 256, 0, stream>>>(hb, w3_b, (float*)d_out, b3, mlpin, 256, 1024, 3);
}

// Round 3
// 434.376 us; speedup vs baseline: 14.7070x; 1.0468x over previous
//
#include <hip/hip_runtime.h>
#include <math.h>

#define D 256
#define S 4096
#define H 8
#define DH 32
#define DM 1024
#define NTOK 8192   // B*S

typedef __attribute__((ext_vector_type(8))) short short8;
typedef __attribute__((ext_vector_type(4))) float f32x4;

// qscale = (1/sqrt(32)) * log2(e): folds softmax scale + exp->exp2 into Q
#define QSCALE (0.17677669529663687f * 1.4426950408889634f)

__device__ inline unsigned short f2bf(float f) {
    union { float f; unsigned u; } v; v.f = f;
    unsigned r = v.u + 0x7fffu + ((v.u >> 16) & 1u);
    return (unsigned short)(r >> 16);
}
__device__ inline void gload16(const void* g, void* l) {
    __builtin_amdgcn_global_load_lds((const __attribute__((address_space(1))) void*)g,
                                     (__attribute__((address_space(3))) void*)l, 16, 0, 0);
}

// ---------------- fp32 -> bf16 conversion for all weights, one launch ----------------
__global__ void conv_all(const float* __restrict__ Wq, const float* __restrict__ Wk,
                         const float* __restrict__ Wv, const float* __restrict__ Wo,
                         const float* __restrict__ W2, const float* __restrict__ W3,
                         unsigned short* __restrict__ wqkv, unsigned short* __restrict__ wo_b,
                         unsigned short* __restrict__ w2_b, unsigned short* __restrict__ w3_b) {
    int i = blockIdx.x * 256 + threadIdx.x;       // 0 .. 786431
    if (i < 196608) {
        const float* s = (i < 65536) ? Wq : ((i < 131072) ? Wk : Wv);
        wqkv[i] = f2bf(s[i & 65535]);
    } else if (i < 262144) {
        wo_b[i - 196608] = f2bf(Wo[i - 196608]);
    } else if (i < 524288) {
        w2_b[i - 262144] = f2bf(W2[i - 262144]);
    } else {
        w3_b[i - 524288] = f2bf(W3[i - 524288]);
    }
}

// ---------------- RoPE cos/sin table: [S][16] ----------------
__global__ void rope_tab(float* __restrict__ ct, float* __restrict__ st) {
    int i = blockIdx.x * 256 + threadIdx.x;       // 0 .. 65535
    int spos = i >> 4, pi = i & 15;
    float inv_freq = powf(10000.0f, -(float)(2 * pi) / 32.0f);
    float fr = (float)spos * inv_freq;
    ct[i] = cosf(fr);
    st[i] = sinf(fr);
}

// ---------------- LayerNorm: fp32 in, bf16 out ----------------
__global__ void ln_kernel(const float* __restrict__ x, const float* __restrict__ g,
                          const float* __restrict__ b, unsigned short* __restrict__ out) {
    __shared__ float red[8];
    int row = blockIdx.x;
    int tid = threadIdx.x;
    float v = x[(size_t)row * D + tid];
    float s = v, s2 = v * v;
    #pragma unroll
    for (int off = 32; off > 0; off >>= 1) {
        s  += __shfl_xor(s, off, 64);
        s2 += __shfl_xor(s2, off, 64);
    }
    int wave = tid >> 6;
    if ((tid & 63) == 0) { red[wave] = s; red[wave + 4] = s2; }
    __syncthreads();
    float sum   = red[0] + red[1] + red[2] + red[3];
    float sumsq = red[4] + red[5] + red[6] + red[7];
    float mu  = sum * (1.0f / D);
    float var = sumsq * (1.0f / D) - mu * mu;
    float rs  = rsqrtf(var + 1e-5f);
    out[(size_t)row * D + tid] = f2bf((v - mu) * rs * g[tid] + b[tid]);
}

// ---------------- bf16 MFMA GEMM: C[M][N] = A[M][K] * Bw[N][K]^T ----------------
// modes: 0 = bf16 store, RoPE applied for cols<512, Q (cols<256) pre-scaled by QSCALE
//        1 = fp32 store acc+res; 2 = bf16 store gelu(acc+bias); 3 = fp32 store acc+bias+res
__global__ __launch_bounds__(256) void gemm_bt(const unsigned short* __restrict__ A,
        const unsigned short* __restrict__ Bw, void* __restrict__ outp,
        const float* __restrict__ bias, const float* __restrict__ res,
        const float* __restrict__ ct, const float* __restrict__ st,
        int N, int K, int mode) {
    __shared__ unsigned short As[128 * 32];
    __shared__ unsigned short Bs[128 * 32];
    int tid = threadIdx.x;
    int w = tid >> 6, l = tid & 63;
    int lm = l & 15, lg = l >> 4;
    int wm = (w >> 1) * 64, wn = (w & 1) * 64;
    int bm = blockIdx.x * 128, bn = blockIdx.y * 128;
    int sr = l >> 2, sk = (l & 3) * 8;
    const unsigned short* Ag = A + (size_t)bm * K;
    const unsigned short* Bg = Bw + (size_t)bn * K;
    f32x4 acc[4][4] = {};

    for (int k0 = 0; k0 < K; k0 += 32) {
        __syncthreads();
        #pragma unroll
        for (int r = 0; r < 2; ++r) {
            int seg = r * 4 + w;
            gload16(Ag + (size_t)(seg * 16 + sr) * K + k0 + sk, &As[seg * 512]);
            gload16(Bg + (size_t)(seg * 16 + sr) * K + k0 + sk, &Bs[seg * 512]);
        }
        __syncthreads();
        short8 af[4], bf[4];
        #pragma unroll
        for (int i = 0; i < 4; ++i) af[i] = *(const short8*)&As[(wm + i * 16 + lm) * 32 + lg * 8];
        #pragma unroll
        for (int i = 0; i < 4; ++i) bf[i] = *(const short8*)&Bs[(wn + i * 16 + lm) * 32 + lg * 8];
        #pragma unroll
        for (int mi = 0; mi < 4; ++mi)
            #pragma unroll
            for (int ni = 0; ni < 4; ++ni)
                acc[mi][ni] = __builtin_amdgcn_mfma_f32_16x16x32_bf16(af[mi], bf[ni], acc[mi][ni], 0, 0, 0);
    }

    if (mode == 0 && bn < 512) {
        // RoPE on q/k columns (wave-uniform branch; shuffles are safe)
        #pragma unroll
        for (int mi = 0; mi < 4; ++mi) {
            #pragma unroll
            for (int ni = 0; ni < 4; ++ni) {
                int ng = bn + wn + ni * 16 + lm;
                int pi = (ng & 31) >> 1;
                float sgn = (ng & 1) ? 1.f : -1.f;
                float qs  = (ng < 256) ? QSCALE : 1.f;
                #pragma unroll
                for (int r2 = 0; r2 < 4; ++r2) {
                    int mg = bm + wm + mi * 16 + lg * 4 + r2;
                    int spos = mg & (S - 1);
                    float vv = acc[mi][ni][r2];
                    float pv = __shfl_xor(vv, 1, 64);
                    float cs = ct[spos * 16 + pi];
                    float sn = st[spos * 16 + pi];
                    float ov = (vv * cs + sgn * pv * sn) * qs;
                    ((unsigned short*)outp)[(size_t)mg * N + ng] = f2bf(ov);
                }
            }
        }
        return;
    }
    #pragma unroll
    for (int mi = 0; mi < 4; ++mi) {
        #pragma unroll
        for (int ni = 0; ni < 4; ++ni) {
            int ng = bn + wn + ni * 16 + lm;
            #pragma unroll
            for (int r2 = 0; r2 < 4; ++r2) {
                int mg = bm + wm + mi * 16 + lg * 4 + r2;
                float v = acc[mi][ni][r2];
                size_t idx = (size_t)mg * N + ng;
                if (mode == 0) {
                    ((unsigned short*)outp)[idx] = f2bf(v);
                } else if (mode == 1) {
                    ((float*)outp)[idx] = v + res[idx];
                } else if (mode == 2) {
                    float t = v + bias[ng];
                    ((unsigned short*)outp)[idx] = f2bf(0.5f * t * (1.0f + erff(t * 0.70710678118654752f)));
                } else {
                    ((float*)outp)[idx] = v + bias[ng] + res[idx];
                }
            }
        }
    }
}

// ---------------- V transpose: Cq v-part -> vt[B][H][DH][S] ----------------
__global__ void vtrans_kernel(const unsigned short* __restrict__ Cq, unsigned short* __restrict__ vt) {
    __shared__ unsigned short Vs[32][72];
    int t = threadIdx.x;
    int sc = blockIdx.x & 63, bh = blockIdx.x >> 6;
    int b = bh >> 3, h = bh & 7;
    int s0 = sc * 64;
    int sl = t >> 2, g = t & 3;
    const unsigned short* src = Cq + (size_t)(b * S + s0 + sl) * 768 + 512 + h * 32 + g * 8;
    short8 u = *(const short8*)src;
    #pragma unroll
    for (int j = 0; j < 8; ++j) Vs[g * 8 + j][sl] = (unsigned short)u[j];
    __syncthreads();
    int dh = t >> 3, c = t & 7;
    short8 vv = *(const short8*)&Vs[dh][c * 8];
    *(short8*)(vt + ((size_t)(bh * 32 + dh)) * S + s0 + c * 8) = vv;
}

// ---------------- MFMA flash attention, fixed-shift-free softmax ----------------
// Q pre-scaled by QSCALE so p = exp2(mfma_score) directly. No online max (scores
// bounded ~|45| in exp2 domain -> no overflow in fp32). k-tiles fully independent.
// block = 4 waves x 16 q rows; grid = B*H*(S/64) = 1024.
__global__ __launch_bounds__(256) void attn_kernel(const unsigned short* __restrict__ Cq,
        const unsigned short* __restrict__ vt, unsigned short* __restrict__ out) {
    __shared__ unsigned short Plds[4][16][40];   // stride 40: b64 writes at bank floor, 16B-aligned b128 reads
    int tid = threadIdx.x;
    int w = tid >> 6, l = tid & 63;
    int lm = l & 15, lg = l >> 4;
    int qt = blockIdx.x & 63;
    int bh = blockIdx.x >> 6;
    int b = bh >> 3, h = bh & 7;
    int q0 = qt * 64 + w * 16;

    const short8 qf = *(const short8*)(Cq + ((size_t)(b * S + q0 + lm)) * 768 + h * DH + lg * 8);
    const unsigned short* kb = Cq + ((size_t)(b * S)) * 768 + 256 + h * DH + lg * 8;
    const unsigned short* vb = vt + ((size_t)bh * DH) * S;
    unsigned short* pp = &Plds[w][lm][0];

    f32x4 o0 = {0.f, 0.f, 0.f, 0.f}, o1 = {0.f, 0.f, 0.f, 0.f};
    float lacc = 0.f;

    #pragma unroll 2
    for (int k0 = 0; k0 < S; k0 += 32) {
        short8 kf0 = *(const short8*)(kb + (size_t)(k0 + lm) * 768);
        short8 kf1 = *(const short8*)(kb + (size_t)(k0 + 16 + lm) * 768);
        short8 va0 = *(const short8*)(vb + (size_t)lm * S + k0 + lg * 8);
        short8 va1 = *(const short8*)(vb + (size_t)(16 + lm) * S + k0 + lg * 8);
        f32x4 z = {0.f, 0.f, 0.f, 0.f};
        f32x4 s0 = __builtin_amdgcn_mfma_f32_16x16x32_bf16(kf0, qf, z, 0, 0, 0);
        f32x4 s1 = __builtin_amdgcn_mfma_f32_16x16x32_bf16(kf1, qf, z, 0, 0, 0);
        unsigned u0[4], u1[4];
        #pragma unroll
        for (int i = 0; i < 4; ++i) {
            float t0 = __builtin_amdgcn_exp2f(s0[i]);
            float t1 = __builtin_amdgcn_exp2f(s1[i]);
            lacc += t0 + t1;
            union { float f; unsigned u; } c0, c1;
            c0.f = t0; c1.f = t1;
            u0[i] = c0.u + 0x8000u;   // round-half-up to bf16
            u1[i] = c1.u + 0x8000u;
        }
        uint2 w0, w1;
        w0.x = __builtin_amdgcn_perm(u0[1], u0[0], 0x07060302u);
        w0.y = __builtin_amdgcn_perm(u0[3], u0[2], 0x07060302u);
        w1.x = __builtin_amdgcn_perm(u1[1], u1[0], 0x07060302u);
        w1.y = __builtin_amdgcn_perm(u1[3], u1[2], 0x07060302u);
        *(uint2*)(pp + lg * 4)      = w0;
        *(uint2*)(pp + 16 + lg * 4) = w1;
        short8 pf = *(const short8*)(pp + lg * 8);
        o0 = __builtin_amdgcn_mfma_f32_16x16x32_bf16(va0, pf, o0, 0, 0, 0);
        o1 = __builtin_amdgcn_mfma_f32_16x16x32_bf16(va1, pf, o1, 0, 0, 0);
    }
    lacc += __shfl_xor(lacc, 16, 64);
    lacc += __shfl_xor(lacc, 32, 64);
    float inv = 1.0f / lacc;
    ushort4 r0, r1;
    r0.x = f2bf(o0[0] * inv); r0.y = f2bf(o0[1] * inv);
    r0.z = f2bf(o0[2] * inv); r0.w = f2bf(o0[3] * inv);
    r1.x = f2bf(o1[0] * inv); r1.y = f2bf(o1[1] * inv);
    r1.z = f2bf(o1[2] * inv); r1.w = f2bf(o1[3] * inv);
    unsigned short* ob = out + ((size_t)(b * S + q0 + lm)) * D + h * DH;
    *(ushort4*)(ob + lg * 4)      = r0;
    *(ushort4*)(ob + 16 + lg * 4) = r1;
}

extern "C" void kernel_launch(void* const* d_in, const int* in_sizes, int n_in,
                              void* d_out, int out_size, void* d_ws, size_t ws_size,
                              hipStream_t stream) {
    const float* x     = (const float*)d_in[0];
    const float* Wq    = (const float*)d_in[1];
    const float* Wk    = (const float*)d_in[2];
    const float* Wv    = (const float*)d_in[3];
    const float* Wo    = (const float*)d_in[4];
    const float* ln1_g = (const float*)d_in[5];
    const float* ln1_b = (const float*)d_in[6];
    const float* ln2_g = (const float*)d_in[7];
    const float* ln2_b = (const float*)d_in[8];
    const float* W2    = (const float*)d_in[9];
    const float* b2    = (const float*)d_in[10];
    const float* W3    = (const float*)d_in[11];
    const float* b3    = (const float*)d_in[12];

    char* w8 = (char*)d_ws;
    unsigned short* wqkv = (unsigned short*)(w8);             // 196608 ush
    unsigned short* wo_b = (unsigned short*)(w8 + 393216);    // 65536
    unsigned short* w2_b = (unsigned short*)(w8 + 524288);    // 262144
    unsigned short* w3_b = (unsigned short*)(w8 + 1048576);   // 262144
    float*          ct   = (float*)(w8 + 1572864);            // 65536 f32
    float*          st   = (float*)(w8 + 1835008);            // 65536 f32
    unsigned short* xn   = (unsigned short*)(w8 + 2097152);   // 2M ush (reused as yn)
    unsigned short* Cq   = (unsigned short*)(w8 + 6291456);   // 6.29M ush (QKV out)
    unsigned short* hb   = Cq;                                // MLP hidden reuses (8.39M ush, 16MB, ends 23068672)
    unsigned short* vtb  = (unsigned short*)(w8 + 23068672);  // 2M ush
    unsigned short* ab   = (unsigned short*)(w8 + 27262976);  // 2M ush
    float*          mlpin= (float*)(w8 + 31457280);           // 2M f32
    unsigned short* yn   = xn;

    conv_all<<<3072, 256, 0, stream>>>(Wq, Wk, Wv, Wo, W2, W3, wqkv, wo_b, w2_b, w3_b);
    rope_tab<<<256, 256, 0, stream>>>(ct, st);
    ln_kernel<<<NTOK, 256, 0, stream>>>(x, ln1_g, ln1_b, xn);
    gemm_bt<<<dim3(64, 6), 256, 0, stream>>>(xn, wqkv, Cq, nullptr, nullptr, ct, st, 768, 256, 0);
    vtrans_kernel<<<1024, 256, 0, stream>>>(Cq, vtb);
    attn_kernel<<<1024, 256, 0, stream>>>(Cq, vtb, ab);
    gemm_bt<<<dim3(64, 2), 256, 0, stream>>>(ab, wo_b, mlpin, nullptr, x, nullptr, nullptr, 256, 256, 1);
    ln_kernel<<<NTOK, 256, 0, stream>>>(mlpin, ln2_g, ln2_b, yn);
    gemm_bt<<<dim3(64, 8), 256, 0, stream>>>(yn, w2_b, hb, b2, nullptr, nullptr, nullptr, 1024, 256, 2);
    gemm_bt<<<dim3(64, 2), 256, 0, stream>>>(hb, w3_b, (float*)d_out, b3, mlpin, nullptr, nullptr, 256, 1024, 3);
}

// Round 4
// 266.722 us; speedup vs baseline: 23.9514x; 1.6286x over previous
//
#include <hip/hip_runtime.h>
#include <math.h>

#define D 256
#define S 4096
#define H 8
#define DH 32
#define DM 1024
#define NTOK 8192   // B*S

typedef __attribute__((ext_vector_type(8))) short short8;
typedef __attribute__((ext_vector_type(4))) float f32x4;

// qscale = (1/sqrt(32)) * log2(e): folds softmax scale + exp->exp2 into Q
#define QSCALE (0.17677669529663687f * 1.4426950408889634f)

__device__ inline unsigned short f2bf(float f) {
    union { float f; unsigned u; } v; v.f = f;
    unsigned r = v.u + 0x7fffu + ((v.u >> 16) & 1u);
    return (unsigned short)(r >> 16);
}
__device__ inline void gload16(const void* g, void* l) {
    __builtin_amdgcn_global_load_lds((const __attribute__((address_space(1))) void*)g,
                                     (__attribute__((address_space(3))) void*)l, 16, 0, 0);
}

// ---------------- fp32 -> bf16 conversion for all weights, one launch ----------------
__global__ void conv_all(const float* __restrict__ Wq, const float* __restrict__ Wk,
                         const float* __restrict__ Wv, const float* __restrict__ Wo,
                         const float* __restrict__ W2, const float* __restrict__ W3,
                         unsigned short* __restrict__ wqkv, unsigned short* __restrict__ wo_b,
                         unsigned short* __restrict__ w2_b, unsigned short* __restrict__ w3_b) {
    int i = blockIdx.x * 256 + threadIdx.x;       // 0 .. 786431
    if (i < 196608) {
        const float* s = (i < 65536) ? Wq : ((i < 131072) ? Wk : Wv);
        wqkv[i] = f2bf(s[i & 65535]);
    } else if (i < 262144) {
        wo_b[i - 196608] = f2bf(Wo[i - 196608]);
    } else if (i < 524288) {
        w2_b[i - 262144] = f2bf(W2[i - 262144]);
    } else {
        w3_b[i - 524288] = f2bf(W3[i - 524288]);
    }
}

// ---------------- RoPE cos/sin table: [S][16] ----------------
__global__ void rope_tab(float* __restrict__ ct, float* __restrict__ st) {
    int i = blockIdx.x * 256 + threadIdx.x;       // 0 .. 65535
    int spos = i >> 4, pi = i & 15;
    float inv_freq = powf(10000.0f, -(float)(2 * pi) / 32.0f);
    float fr = (float)spos * inv_freq;
    ct[i] = cosf(fr);
    st[i] = sinf(fr);
}

// ---------------- LayerNorm: fp32 in, bf16 out ----------------
__global__ void ln_kernel(const float* __restrict__ x, const float* __restrict__ g,
                          const float* __restrict__ b, unsigned short* __restrict__ out) {
    __shared__ float red[8];
    int row = blockIdx.x;
    int tid = threadIdx.x;
    float v = x[(size_t)row * D + tid];
    float s = v, s2 = v * v;
    #pragma unroll
    for (int off = 32; off > 0; off >>= 1) {
        s  += __shfl_xor(s, off, 64);
        s2 += __shfl_xor(s2, off, 64);
    }
    int wave = tid >> 6;
    if ((tid & 63) == 0) { red[wave] = s; red[wave + 4] = s2; }
    __syncthreads();
    float sum   = red[0] + red[1] + red[2] + red[3];
    float sumsq = red[4] + red[5] + red[6] + red[7];
    float mu  = sum * (1.0f / D);
    float var = sumsq * (1.0f / D) - mu * mu;
    float rs  = rsqrtf(var + 1e-5f);
    out[(size_t)row * D + tid] = f2bf((v - mu) * rs * g[tid] + b[tid]);
}

// ---------------- bf16 MFMA GEMM, 64x64 tile: C[M][N] = A[M][K] * Bw[N][K]^T --------
// modes: 0 = bf16 store, RoPE applied for cols<512, Q (cols<256) pre-scaled by QSCALE
//        1 = fp32 store acc+res; 2 = bf16 store gelu(acc+bias); 3 = fp32 store acc+bias+res
__global__ __launch_bounds__(256) void gemm64(const unsigned short* __restrict__ A,
        const unsigned short* __restrict__ Bw, void* __restrict__ outp,
        const float* __restrict__ bias, const float* __restrict__ res,
        const float* __restrict__ ct, const float* __restrict__ st,
        int N, int K, int mode) {
    __shared__ unsigned short As[64 * 32];
    __shared__ unsigned short Bs[64 * 32];
    int tid = threadIdx.x;
    int w = tid >> 6, l = tid & 63;
    int lm = l & 15, lg = l >> 4;
    int wm = (w >> 1) * 32, wn = (w & 1) * 32;
    int bm = blockIdx.x * 64, bn = blockIdx.y * 64;
    int sr = l >> 2, sk = (l & 3) * 8;
    const unsigned short* Ag = A + (size_t)(bm + w * 16 + sr) * K + sk;
    const unsigned short* Bg = Bw + (size_t)(bn + w * 16 + sr) * K + sk;
    f32x4 acc[2][2] = {};

    for (int k0 = 0; k0 < K; k0 += 32) {
        __syncthreads();
        gload16(Ag + k0, &As[w * 512]);
        gload16(Bg + k0, &Bs[w * 512]);
        __syncthreads();
        short8 af[2], bf[2];
        #pragma unroll
        for (int i = 0; i < 2; ++i) af[i] = *(const short8*)&As[(wm + i * 16 + lm) * 32 + lg * 8];
        #pragma unroll
        for (int i = 0; i < 2; ++i) bf[i] = *(const short8*)&Bs[(wn + i * 16 + lm) * 32 + lg * 8];
        #pragma unroll
        for (int mi = 0; mi < 2; ++mi)
            #pragma unroll
            for (int ni = 0; ni < 2; ++ni)
                acc[mi][ni] = __builtin_amdgcn_mfma_f32_16x16x32_bf16(af[mi], bf[ni], acc[mi][ni], 0, 0, 0);
    }

    if (mode == 0 && bn < 512) {
        // RoPE on q/k columns (wave-uniform branch; shuffles are safe)
        #pragma unroll
        for (int mi = 0; mi < 2; ++mi) {
            #pragma unroll
            for (int ni = 0; ni < 2; ++ni) {
                int ng = bn + wn + ni * 16 + lm;
                int pi = (ng & 31) >> 1;
                float sgn = (ng & 1) ? 1.f : -1.f;
                float qs  = (ng < 256) ? QSCALE : 1.f;
                #pragma unroll
                for (int r2 = 0; r2 < 4; ++r2) {
                    int mg = bm + wm + mi * 16 + lg * 4 + r2;
                    int spos = mg & (S - 1);
                    float vv = acc[mi][ni][r2];
                    float pv = __shfl_xor(vv, 1, 64);
                    float cs = ct[spos * 16 + pi];
                    float sn = st[spos * 16 + pi];
                    float ov = (vv * cs + sgn * pv * sn) * qs;
                    ((unsigned short*)outp)[(size_t)mg * N + ng] = f2bf(ov);
                }
            }
        }
        return;
    }
    #pragma unroll
    for (int mi = 0; mi < 2; ++mi) {
        #pragma unroll
        for (int ni = 0; ni < 2; ++ni) {
            int ng = bn + wn + ni * 16 + lm;
            #pragma unroll
            for (int r2 = 0; r2 < 4; ++r2) {
                int mg = bm + wm + mi * 16 + lg * 4 + r2;
                float v = acc[mi][ni][r2];
                size_t idx = (size_t)mg * N + ng;
                if (mode == 0) {
                    ((unsigned short*)outp)[idx] = f2bf(v);
                } else if (mode == 1) {
                    ((float*)outp)[idx] = v + res[idx];
                } else if (mode == 2) {
                    float t = v + bias[ng];
                    ((unsigned short*)outp)[idx] = f2bf(0.5f * t * (1.0f + erff(t * 0.70710678118654752f)));
                } else {
                    ((float*)outp)[idx] = v + bias[ng] + res[idx];
                }
            }
        }
    }
}

// ---------------- V transpose: Cq v-part -> vt[B][H][DH][S] ----------------
__global__ void vtrans_kernel(const unsigned short* __restrict__ Cq, unsigned short* __restrict__ vt) {
    __shared__ unsigned short Vs[32][72];
    int t = threadIdx.x;
    int sc = blockIdx.x & 63, bh = blockIdx.x >> 6;
    int b = bh >> 3, h = bh & 7;
    int s0 = sc * 64;
    int sl = t >> 2, g = t & 3;
    const unsigned short* src = Cq + (size_t)(b * S + s0 + sl) * 768 + 512 + h * 32 + g * 8;
    short8 u = *(const short8*)src;
    #pragma unroll
    for (int j = 0; j < 8; ++j) Vs[g * 8 + j][sl] = (unsigned short)u[j];
    __syncthreads();
    int dh = t >> 3, c = t & 7;
    short8 vv = *(const short8*)&Vs[dh][c * 8];
    *(short8*)(vt + ((size_t)(bh * 32 + dh)) * S + s0 + c * 8) = vv;
}

// ---------------- MFMA flash attention: LDS-staged K/V, shift-free softmax --------
// block = 4 waves x 16 q rows = 64 q rows; 64 keys per iteration, K/V staged via
// global_load_lds (coalesced, shared across the 4 waves). Softmax denominator comes
// free from the PV MFMA via a bf16 ones-row appended to the V^T tile.
// grid = B*H*(S/64) = 1024.
__global__ __launch_bounds__(256) void attn_kernel(const unsigned short* __restrict__ Cq,
        const unsigned short* __restrict__ vt, unsigned short* __restrict__ out) {
    __shared__ unsigned short Ks[64][32];        // [key][dim]
    __shared__ unsigned short Vs[48][64];        // [dim][key]; rows 32..47: ones-row + zeros
    __shared__ unsigned short Plds[4][16][40];   // per-wave P^T staging, 32 keys/round
    int tid = threadIdx.x;
    int w = tid >> 6, l = tid & 63;
    int lm = l & 15, lg = l >> 4;
    int qt = blockIdx.x & 63;
    int bh = blockIdx.x >> 6;
    int b = bh >> 3, h = bh & 7;
    int q0 = qt * 64 + w * 16;

    const short8 qf = *(const short8*)(Cq + ((size_t)(b * S + q0 + lm)) * 768 + h * DH + lg * 8);
    const unsigned short* kg = Cq + ((size_t)(b * S)) * 768 + 256 + h * 32
                               + (size_t)(w * 16 + (l >> 2)) * 768 + (l & 3) * 8;
    const unsigned short* vg = vt + ((size_t)(bh * 32 + w * 8 + (l >> 3))) * S + (l & 7) * 8;
    unsigned short* kl = &Ks[w * 16][0];
    unsigned short* vl = &Vs[w * 8][0];
    unsigned short* pp = &Plds[w][lm][0];

    // static ones/zero rows of Vs (rows 32..47)
    {
        unsigned short val = (tid < 16) ? (unsigned short)0x3F80 : (unsigned short)0;
        ushort4 v4 = make_ushort4(val, val, val, val);
        *(ushort4*)(&Vs[0][0] + 2048 + tid * 4) = v4;
    }

    f32x4 o0 = {0.f, 0.f, 0.f, 0.f}, o1 = {0.f, 0.f, 0.f, 0.f}, o2 = {0.f, 0.f, 0.f, 0.f};
    const f32x4 z = {0.f, 0.f, 0.f, 0.f};

    for (int k0 = 0; k0 < S; k0 += 64) {
        __syncthreads();
        gload16(kg + (size_t)k0 * 768, kl);
        gload16(vg + k0, vl);
        __syncthreads();
        #pragma unroll
        for (int half = 0; half < 2; ++half) {
            short8 kf0 = *(const short8*)&Ks[half * 32 + lm][lg * 8];
            short8 kf1 = *(const short8*)&Ks[half * 32 + 16 + lm][lg * 8];
            f32x4 s0 = __builtin_amdgcn_mfma_f32_16x16x32_bf16(kf0, qf, z, 0, 0, 0);
            f32x4 s1 = __builtin_amdgcn_mfma_f32_16x16x32_bf16(kf1, qf, z, 0, 0, 0);
            unsigned u0[4], u1[4];
            #pragma unroll
            for (int i = 0; i < 4; ++i) {
                float t0 = __builtin_amdgcn_exp2f(s0[i]);
                float t1 = __builtin_amdgcn_exp2f(s1[i]);
                union { float f; unsigned u; } c0, c1;
                c0.f = t0; c1.f = t1;
                u0[i] = c0.u + 0x8000u;   // round-half-up to bf16
                u1[i] = c1.u + 0x8000u;
            }
            uint2 w0, w1;
            w0.x = __builtin_amdgcn_perm(u0[1], u0[0], 0x07060302u);
            w0.y = __builtin_amdgcn_perm(u0[3], u0[2], 0x07060302u);
            w1.x = __builtin_amdgcn_perm(u1[1], u1[0], 0x07060302u);
            w1.y = __builtin_amdgcn_perm(u1[3], u1[2], 0x07060302u);
            *(uint2*)(pp + lg * 4)      = w0;
            *(uint2*)(pp + 16 + lg * 4) = w1;
            short8 pf  = *(const short8*)(pp + lg * 8);
            short8 va0 = *(const short8*)&Vs[lm][half * 32 + lg * 8];
            short8 va1 = *(const short8*)&Vs[16 + lm][half * 32 + lg * 8];
            short8 va2 = *(const short8*)&Vs[32 + lm][half * 32 + lg * 8];
            o0 = __builtin_amdgcn_mfma_f32_16x16x32_bf16(va0, pf, o0, 0, 0, 0);
            o1 = __builtin_amdgcn_mfma_f32_16x16x32_bf16(va1, pf, o1, 0, 0, 0);
            o2 = __builtin_amdgcn_mfma_f32_16x16x32_bf16(va2, pf, o2, 0, 0, 0);
        }
    }
    // softmax denominator for q=lm sits in lane lm (lg=0, reg 0) of o2
    float lsum = __shfl(o2[0], lm, 64);
    float inv = 1.0f / lsum;
    ushort4 r0, r1;
    r0.x = f2bf(o0[0] * inv); r0.y = f2bf(o0[1] * inv);
    r0.z = f2bf(o0[2] * inv); r0.w = f2bf(o0[3] * inv);
    r1.x = f2bf(o1[0] * inv); r1.y = f2bf(o1[1] * inv);
    r1.z = f2bf(o1[2] * inv); r1.w = f2bf(o1[3] * inv);
    unsigned short* ob = out + ((size_t)(b * S + q0 + lm)) * D + h * DH;
    *(ushort4*)(ob + lg * 4)      = r0;
    *(ushort4*)(ob + 16 + lg * 4) = r1;
}

extern "C" void kernel_launch(void* const* d_in, const int* in_sizes, int n_in,
                              void* d_out, int out_size, void* d_ws, size_t ws_size,
                              hipStream_t stream) {
    const float* x     = (const float*)d_in[0];
    const float* Wq    = (const float*)d_in[1];
    const float* Wk    = (const float*)d_in[2];
    const float* Wv    = (const float*)d_in[3];
    const float* Wo    = (const float*)d_in[4];
    const float* ln1_g = (const float*)d_in[5];
    const float* ln1_b = (const float*)d_in[6];
    const float* ln2_g = (const float*)d_in[7];
    const float* ln2_b = (const float*)d_in[8];
    const float* W2    = (const float*)d_in[9];
    const float* b2    = (const float*)d_in[10];
    const float* W3    = (const float*)d_in[11];
    const float* b3    = (const float*)d_in[12];

    char* w8 = (char*)d_ws;
    unsigned short* wqkv = (unsigned short*)(w8);             // 196608 ush
    unsigned short* wo_b = (unsigned short*)(w8 + 393216);    // 65536
    unsigned short* w2_b = (unsigned short*)(w8 + 524288);    // 262144
    unsigned short* w3_b = (unsigned short*)(w8 + 1048576);   // 262144
    float*          ct   = (float*)(w8 + 1572864);            // 65536 f32
    float*          st   = (float*)(w8 + 1835008);            // 65536 f32
    unsigned short* xn   = (unsigned short*)(w8 + 2097152);   // 2M ush (reused as yn)
    unsigned short* Cq   = (unsigned short*)(w8 + 6291456);   // 6.29M ush (QKV out)
    unsigned short* hb   = Cq;                                // MLP hidden reuses (16MB)
    unsigned short* vtb  = (unsigned short*)(w8 + 23068672);  // 2M ush
    unsigned short* ab   = (unsigned short*)(w8 + 27262976);  // 2M ush
    float*          mlpin= (float*)(w8 + 31457280);           // 2M f32
    unsigned short* yn   = xn;

    conv_all<<<3072, 256, 0, stream>>>(Wq, Wk, Wv, Wo, W2, W3, wqkv, wo_b, w2_b, w3_b);
    rope_tab<<<256, 256, 0, stream>>>(ct, st);
    ln_kernel<<<NTOK, 256, 0, stream>>>(x, ln1_g, ln1_b, xn);
    gemm64<<<dim3(128, 12), 256, 0, stream>>>(xn, wqkv, Cq, nullptr, nullptr, ct, st, 768, 256, 0);
    vtrans_kernel<<<1024, 256, 0, stream>>>(Cq, vtb);
    attn_kernel<<<1024, 256, 0, stream>>>(Cq, vtb, ab);
    gemm64<<<dim3(128, 4), 256, 0, stream>>>(ab, wo_b, mlpin, nullptr, x, nullptr, nullptr, 256, 256, 1);
    ln_kernel<<<NTOK, 256, 0, stream>>>(mlpin, ln2_g, ln2_b, yn);
    gemm64<<<dim3(128, 16), 256, 0, stream>>>(yn, w2_b, hb, b2, nullptr, nullptr, nullptr, 1024, 256, 2);
    gemm64<<<dim3(128, 4), 256, 0, stream>>>(hb, w3_b, (float*)d_out, b3, mlpin, nullptr, nullptr, 256, 1024, 3);
}

// Round 5
// 234.432 us; speedup vs baseline: 27.2503x; 1.1377x over previous
//
#include <hip/hip_runtime.h>
#include <math.h>

#define D 256
#define S 4096
#define H 8
#define DH 32
#define DM 1024
#define NTOK 8192   // B*S

typedef __attribute__((ext_vector_type(8))) short short8;
typedef __attribute__((ext_vector_type(4))) float f32x4;

// qscale = (1/sqrt(32)) * log2(e): folds softmax scale + exp->exp2 into Q
#define QSCALE (0.17677669529663687f * 1.4426950408889634f)

__device__ inline unsigned short f2bf(float f) {
    union { float f; unsigned u; } v; v.f = f;
    unsigned r = v.u + 0x7fffu + ((v.u >> 16) & 1u);
    return (unsigned short)(r >> 16);
}
__device__ inline void gload16(const void* g, void* l) {
    __builtin_amdgcn_global_load_lds((const __attribute__((address_space(1))) void*)g,
                                     (__attribute__((address_space(3))) void*)l, 16, 0, 0);
}

// ---------------- fp32 -> bf16 conversion for all weights, one launch ----------------
__global__ void conv_all(const float* __restrict__ Wq, const float* __restrict__ Wk,
                         const float* __restrict__ Wv, const float* __restrict__ Wo,
                         const float* __restrict__ W2, const float* __restrict__ W3,
                         unsigned short* __restrict__ wqkv, unsigned short* __restrict__ wo_b,
                         unsigned short* __restrict__ w2_b, unsigned short* __restrict__ w3_b) {
    int i = blockIdx.x * 256 + threadIdx.x;       // 0 .. 786431
    if (i < 196608) {
        const float* s = (i < 65536) ? Wq : ((i < 131072) ? Wk : Wv);
        wqkv[i] = f2bf(s[i & 65535]);
    } else if (i < 262144) {
        wo_b[i - 196608] = f2bf(Wo[i - 196608]);
    } else if (i < 524288) {
        w2_b[i - 262144] = f2bf(W2[i - 262144]);
    } else {
        w3_b[i - 524288] = f2bf(W3[i - 524288]);
    }
}

// ---------------- RoPE cos/sin table: [S][16] ----------------
__global__ void rope_tab(float* __restrict__ ct, float* __restrict__ st) {
    int i = blockIdx.x * 256 + threadIdx.x;       // 0 .. 65535
    int spos = i >> 4, pi = i & 15;
    float inv_freq = powf(10000.0f, -(float)(2 * pi) / 32.0f);
    float fr = (float)spos * inv_freq;
    ct[i] = cosf(fr);
    st[i] = sinf(fr);
}

// ---------------- LayerNorm: fp32 in, bf16 out ----------------
__global__ void ln_kernel(const float* __restrict__ x, const float* __restrict__ g,
                          const float* __restrict__ b, unsigned short* __restrict__ out) {
    __shared__ float red[8];
    int row = blockIdx.x;
    int tid = threadIdx.x;
    float v = x[(size_t)row * D + tid];
    float s = v, s2 = v * v;
    #pragma unroll
    for (int off = 32; off > 0; off >>= 1) {
        s  += __shfl_xor(s, off, 64);
        s2 += __shfl_xor(s2, off, 64);
    }
    int wave = tid >> 6;
    if ((tid & 63) == 0) { red[wave] = s; red[wave + 4] = s2; }
    __syncthreads();
    float sum   = red[0] + red[1] + red[2] + red[3];
    float sumsq = red[4] + red[5] + red[6] + red[7];
    float mu  = sum * (1.0f / D);
    float var = sumsq * (1.0f / D) - mu * mu;
    float rs  = rsqrtf(var + 1e-5f);
    out[(size_t)row * D + tid] = f2bf((v - mu) * rs * g[tid] + b[tid]);
}

// ---------------- bf16 MFMA GEMM, 64x64 tile: C[M][N] = A[M][K] * Bw[N][K]^T --------
// modes: 0 = bf16 store, RoPE applied for cols<512, Q (cols<256) pre-scaled by QSCALE
//        1 = fp32 store acc+res; 2 = bf16 store gelu(acc+bias); 3 = fp32 store acc+bias+res
__global__ __launch_bounds__(256) void gemm64(const unsigned short* __restrict__ A,
        const unsigned short* __restrict__ Bw, void* __restrict__ outp,
        const float* __restrict__ bias, const float* __restrict__ res,
        const float* __restrict__ ct, const float* __restrict__ st,
        int N, int K, int mode) {
    __shared__ unsigned short As[64 * 32];
    __shared__ unsigned short Bs[64 * 32];
    int tid = threadIdx.x;
    int w = tid >> 6, l = tid & 63;
    int lm = l & 15, lg = l >> 4;
    int wm = (w >> 1) * 32, wn = (w & 1) * 32;
    int bm = blockIdx.x * 64, bn = blockIdx.y * 64;
    int sr = l >> 2, sk = (l & 3) * 8;
    const unsigned short* Ag = A + (size_t)(bm + w * 16 + sr) * K + sk;
    const unsigned short* Bg = Bw + (size_t)(bn + w * 16 + sr) * K + sk;
    f32x4 acc[2][2] = {};

    for (int k0 = 0; k0 < K; k0 += 32) {
        __syncthreads();
        gload16(Ag + k0, &As[w * 512]);
        gload16(Bg + k0, &Bs[w * 512]);
        __syncthreads();
        short8 af[2], bf[2];
        #pragma unroll
        for (int i = 0; i < 2; ++i) af[i] = *(const short8*)&As[(wm + i * 16 + lm) * 32 + lg * 8];
        #pragma unroll
        for (int i = 0; i < 2; ++i) bf[i] = *(const short8*)&Bs[(wn + i * 16 + lm) * 32 + lg * 8];
        #pragma unroll
        for (int mi = 0; mi < 2; ++mi)
            #pragma unroll
            for (int ni = 0; ni < 2; ++ni)
                acc[mi][ni] = __builtin_amdgcn_mfma_f32_16x16x32_bf16(af[mi], bf[ni], acc[mi][ni], 0, 0, 0);
    }

    if (mode == 0 && bn < 512) {
        // RoPE on q/k columns (wave-uniform branch; shuffles are safe)
        #pragma unroll
        for (int mi = 0; mi < 2; ++mi) {
            #pragma unroll
            for (int ni = 0; ni < 2; ++ni) {
                int ng = bn + wn + ni * 16 + lm;
                int pi = (ng & 31) >> 1;
                float sgn = (ng & 1) ? 1.f : -1.f;
                float qs  = (ng < 256) ? QSCALE : 1.f;
                #pragma unroll
                for (int r2 = 0; r2 < 4; ++r2) {
                    int mg = bm + wm + mi * 16 + lg * 4 + r2;
                    int spos = mg & (S - 1);
                    float vv = acc[mi][ni][r2];
                    float pv = __shfl_xor(vv, 1, 64);
                    float cs = ct[spos * 16 + pi];
                    float sn = st[spos * 16 + pi];
                    float ov = (vv * cs + sgn * pv * sn) * qs;
                    ((unsigned short*)outp)[(size_t)mg * N + ng] = f2bf(ov);
                }
            }
        }
        return;
    }
    #pragma unroll
    for (int mi = 0; mi < 2; ++mi) {
        #pragma unroll
        for (int ni = 0; ni < 2; ++ni) {
            int ng = bn + wn + ni * 16 + lm;
            #pragma unroll
            for (int r2 = 0; r2 < 4; ++r2) {
                int mg = bm + wm + mi * 16 + lg * 4 + r2;
                float v = acc[mi][ni][r2];
                size_t idx = (size_t)mg * N + ng;
                if (mode == 0) {
                    ((unsigned short*)outp)[idx] = f2bf(v);
                } else if (mode == 1) {
                    ((float*)outp)[idx] = v + res[idx];
                } else if (mode == 2) {
                    float t = v + bias[ng];
                    ((unsigned short*)outp)[idx] = f2bf(0.5f * t * (1.0f + erff(t * 0.70710678118654752f)));
                } else {
                    ((float*)outp)[idx] = v + bias[ng] + res[idx];
                }
            }
        }
    }
}

// ---------------- V transpose: Cq v-part -> vt[B][H][DH][S] ----------------
__global__ void vtrans_kernel(const unsigned short* __restrict__ Cq, unsigned short* __restrict__ vt) {
    __shared__ unsigned short Vs[32][72];
    int t = threadIdx.x;
    int sc = blockIdx.x & 63, bh = blockIdx.x >> 6;
    int b = bh >> 3, h = bh & 7;
    int s0 = sc * 64;
    int sl = t >> 2, g = t & 3;
    const unsigned short* src = Cq + (size_t)(b * S + s0 + sl) * 768 + 512 + h * 32 + g * 8;
    short8 u = *(const short8*)src;
    #pragma unroll
    for (int j = 0; j < 8; ++j) Vs[g * 8 + j][sl] = (unsigned short)u[j];
    __syncthreads();
    int dh = t >> 3, c = t & 7;
    short8 vv = *(const short8*)&Vs[dh][c * 8];
    *(short8*)(vt + ((size_t)(bh * 32 + dh)) * S + s0 + c * 8) = vv;
}

// ---------------- MFMA flash attention: swizzled LDS staging + double buffer ------
// XOR-swizzled tile layouts make all b128 LDS reads bank-conflict-free while staying
// compatible with global_load_lds' fixed lane->LDS mapping (we permute the *global*
// chunk each lane fetches instead). K phys chunk = c ^ ((key>>1)&3); V phys chunk =
// c ^ (dim&7). Softmax denominator rides the PV MFMA via a constant ones-row tile
// (content invariant under swizzle). Double-buffered staging: one barrier per tile,
// prefetch issued a full compute-phase before its vmcnt drain.
// block = 4 waves x 16 q rows = 64 q rows; grid = B*H*(S/64) = 1024.
__global__ __launch_bounds__(256) void attn_kernel(const unsigned short* __restrict__ Cq,
        const unsigned short* __restrict__ vt, unsigned short* __restrict__ out) {
    __shared__ unsigned short Ks[2][64][32];     // [buf][key][dim]   (swizzled chunks)
    __shared__ unsigned short Vs[2][32][64];     // [buf][dim][key]   (swizzled chunks)
    __shared__ unsigned short Ones[16][64];      // row 0 = 1.0bf16, rest 0
    __shared__ unsigned short Plds[4][16][40];   // per-wave P^T staging (stride 80B: conflict-free)
    int tid = threadIdx.x;
    int w = tid >> 6, l = tid & 63;
    int lm = l & 15, lg = l >> 4;
    int qt = blockIdx.x & 63;
    int bh = blockIdx.x >> 6;
    int b = bh >> 3, h = bh & 7;
    int q0 = qt * 64 + w * 16;

    {   // ones tile init (16x64 ushorts = 256 lanes x 4)
        unsigned short val = (tid < 16) ? (unsigned short)0x3F80 : (unsigned short)0;
        *(ushort4*)(&Ones[0][0] + tid * 4) = make_ushort4(val, val, val, val);
    }

    const short8 qf = *(const short8*)(Cq + ((size_t)(b * S + q0 + lm)) * 768 + h * DH + lg * 8);
    // swizzle-adjusted global staging addresses (lane -> fixed LDS slot)
    const unsigned short* kg = Cq + ((size_t)(b * S)) * 768 + 256 + h * 32
                               + (size_t)(w * 16 + (l >> 2)) * 768 + ((l & 3) ^ ((l >> 3) & 3)) * 8;
    const unsigned short* vg = vt + ((size_t)(bh * 32 + w * 8 + (l >> 3))) * S + ((l & 7) ^ (l >> 3)) * 8;
    unsigned short* pp = &Plds[w][lm][0];
    const int kswz = (lm >> 1) & 3;
    const int vswz = lm & 7;

    f32x4 o0 = {0.f, 0.f, 0.f, 0.f}, o1 = {0.f, 0.f, 0.f, 0.f}, o2 = {0.f, 0.f, 0.f, 0.f};
    const f32x4 z = {0.f, 0.f, 0.f, 0.f};

    // prefetch tile 0 into buffer 0
    gload16(kg, &Ks[0][w * 16][0]);
    gload16(vg, &Vs[0][w * 8][0]);

    #pragma unroll 2
    for (int it = 0; it < S / 64; ++it) {
        int cur = it & 1;
        __syncthreads();   // drains prefetch of tile it; orders reads of buf[1-cur] from it-1
        if (it + 1 < S / 64) {
            gload16(kg + (size_t)(it + 1) * 64 * 768, &Ks[1 - cur][w * 16][0]);
            gload16(vg + (size_t)(it + 1) * 64,       &Vs[1 - cur][w * 8][0]);
        }
        #pragma unroll
        for (int half = 0; half < 2; ++half) {
            short8 kf0 = *(const short8*)&Ks[cur][half * 32 + lm][(lg ^ kswz) * 8];
            short8 kf1 = *(const short8*)&Ks[cur][half * 32 + 16 + lm][(lg ^ kswz) * 8];
            f32x4 s0 = __builtin_amdgcn_mfma_f32_16x16x32_bf16(kf0, qf, z, 0, 0, 0);
            f32x4 s1 = __builtin_amdgcn_mfma_f32_16x16x32_bf16(kf1, qf, z, 0, 0, 0);
            unsigned u0[4], u1[4];
            #pragma unroll
            for (int i = 0; i < 4; ++i) {
                float t0 = __builtin_amdgcn_exp2f(s0[i]);
                float t1 = __builtin_amdgcn_exp2f(s1[i]);
                union { float f; unsigned u; } c0, c1;
                c0.f = t0; c1.f = t1;
                u0[i] = c0.u + 0x8000u;   // round-half-up to bf16
                u1[i] = c1.u + 0x8000u;
            }
            uint2 w0, w1;
            w0.x = __builtin_amdgcn_perm(u0[1], u0[0], 0x07060302u);
            w0.y = __builtin_amdgcn_perm(u0[3], u0[2], 0x07060302u);
            w1.x = __builtin_amdgcn_perm(u1[1], u1[0], 0x07060302u);
            w1.y = __builtin_amdgcn_perm(u1[3], u1[2], 0x07060302u);
            *(uint2*)(pp + lg * 4)      = w0;
            *(uint2*)(pp + 16 + lg * 4) = w1;
            short8 pf  = *(const short8*)(pp + lg * 8);
            int vc = ((half * 4 + lg) ^ vswz) * 8;
            short8 va0 = *(const short8*)&Vs[cur][lm][vc];
            short8 va1 = *(const short8*)&Vs[cur][16 + lm][vc];
            short8 va2 = *(const short8*)&Ones[lm][vc];
            o0 = __builtin_amdgcn_mfma_f32_16x16x32_bf16(va0, pf, o0, 0, 0, 0);
            o1 = __builtin_amdgcn_mfma_f32_16x16x32_bf16(va1, pf, o1, 0, 0, 0);
            o2 = __builtin_amdgcn_mfma_f32_16x16x32_bf16(va2, pf, o2, 0, 0, 0);
        }
    }
    // softmax denominator for q=lm sits in lane lm (lg=0, reg 0) of o2
    float lsum = __shfl(o2[0], lm, 64);
    float inv = 1.0f / lsum;
    ushort4 r0, r1;
    r0.x = f2bf(o0[0] * inv); r0.y = f2bf(o0[1] * inv);
    r0.z = f2bf(o0[2] * inv); r0.w = f2bf(o0[3] * inv);
    r1.x = f2bf(o1[0] * inv); r1.y = f2bf(o1[1] * inv);
    r1.z = f2bf(o1[2] * inv); r1.w = f2bf(o1[3] * inv);
    unsigned short* ob = out + ((size_t)(b * S + q0 + lm)) * D + h * DH;
    *(ushort4*)(ob + lg * 4)      = r0;
    *(ushort4*)(ob + 16 + lg * 4) = r1;
}

extern "C" void kernel_launch(void* const* d_in, const int* in_sizes, int n_in,
                              void* d_out, int out_size, void* d_ws, size_t ws_size,
                              hipStream_t stream) {
    const float* x     = (const float*)d_in[0];
    const float* Wq    = (const float*)d_in[1];
    const float* Wk    = (const float*)d_in[2];
    const float* Wv    = (const float*)d_in[3];
    const float* Wo    = (const float*)d_in[4];
    const float* ln1_g = (const float*)d_in[5];
    const float* ln1_b = (const float*)d_in[6];
    const float* ln2_g = (const float*)d_in[7];
    const float* ln2_b = (const float*)d_in[8];
    const float* W2    = (const float*)d_in[9];
    const float* b2    = (const float*)d_in[10];
    const float* W3    = (const float*)d_in[11];
    const float* b3    = (const float*)d_in[12];

    char* w8 = (char*)d_ws;
    unsigned short* wqkv = (unsigned short*)(w8);             // 196608 ush
    unsigned short* wo_b = (unsigned short*)(w8 + 393216);    // 65536
    unsigned short* w2_b = (unsigned short*)(w8 + 524288);    // 262144
    unsigned short* w3_b = (unsigned short*)(w8 + 1048576);   // 262144
    float*          ct   = (float*)(w8 + 1572864);            // 65536 f32
    float*          st   = (float*)(w8 + 1835008);            // 65536 f32
    unsigned short* xn   = (unsigned short*)(w8 + 2097152);   // 2M ush (reused as yn)
    unsigned short* Cq   = (unsigned short*)(w8 + 6291456);   // 6.29M ush (QKV out)
    unsigned short* hb   = Cq;                                // MLP hidden reuses (16MB)
    unsigned short* vtb  = (unsigned short*)(w8 + 23068672);  // 2M ush
    unsigned short* ab   = (unsigned short*)(w8 + 27262976);  // 2M ush
    float*          mlpin= (float*)(w8 + 31457280);           // 2M f32
    unsigned short* yn   = xn;

    conv_all<<<3072, 256, 0, stream>>>(Wq, Wk, Wv, Wo, W2, W3, wqkv, wo_b, w2_b, w3_b);
    rope_tab<<<256, 256, 0, stream>>>(ct, st);
    ln_kernel<<<NTOK, 256, 0, stream>>>(x, ln1_g, ln1_b, xn);
    gemm64<<<dim3(128, 12), 256, 0, stream>>>(xn, wqkv, Cq, nullptr, nullptr, ct, st, 768, 256, 0);
    vtrans_kernel<<<1024, 256, 0, stream>>>(Cq, vtb);
    attn_kernel<<<1024, 256, 0, stream>>>(Cq, vtb, ab);
    gemm64<<<dim3(128, 4), 256, 0, stream>>>(ab, wo_b, mlpin, nullptr, x, nullptr, nullptr, 256, 256, 1);
    ln_kernel<<<NTOK, 256, 0, stream>>>(mlpin, ln2_g, ln2_b, yn);
    gemm64<<<dim3(128, 16), 256, 0, stream>>>(yn, w2_b, hb, b2, nullptr, nullptr, nullptr, 1024, 256, 2);
    gemm64<<<dim3(128, 4), 256, 0, stream>>>(hb, w3_b, (float*)d_out, b3, mlpin, nullptr, nullptr, 256, 1024, 3);
}

// Round 6
// 219.179 us; speedup vs baseline: 29.1468x; 1.0696x over previous
//
#include <hip/hip_runtime.h>
#include <math.h>

#define D 256
#define S 4096
#define H 8
#define DH 32
#define DM 1024
#define NTOK 8192   // B*S

typedef __attribute__((ext_vector_type(8))) short short8;
typedef __attribute__((ext_vector_type(4))) float f32x4;

// qscale = (1/sqrt(32)) * log2(e): folds softmax scale + exp->exp2 into Q
#define QSCALE (0.17677669529663687f * 1.4426950408889634f)

__device__ inline unsigned short f2bf(float f) {
    union { float f; unsigned u; } v; v.f = f;
    unsigned r = v.u + 0x7fffu + ((v.u >> 16) & 1u);
    return (unsigned short)(r >> 16);
}
__device__ inline void gload16(const void* g, void* l) {
    __builtin_amdgcn_global_load_lds((const __attribute__((address_space(1))) void*)g,
                                     (__attribute__((address_space(3))) void*)l, 16, 0, 0);
}

// -------- fp32 -> bf16 weights + RoPE cos/sin table, one launch --------
__global__ void conv_all(const float* __restrict__ Wq, const float* __restrict__ Wk,
                         const float* __restrict__ Wv, const float* __restrict__ Wo,
                         const float* __restrict__ W2, const float* __restrict__ W3,
                         unsigned short* __restrict__ wqkv, unsigned short* __restrict__ wo_b,
                         unsigned short* __restrict__ w2_b, unsigned short* __restrict__ w3_b,
                         float* __restrict__ ct, float* __restrict__ st) {
    int i = blockIdx.x * 256 + threadIdx.x;       // 0 .. 851967
    if (i < 196608) {
        const float* s = (i < 65536) ? Wq : ((i < 131072) ? Wk : Wv);
        wqkv[i] = f2bf(s[i & 65535]);
    } else if (i < 262144) {
        wo_b[i - 196608] = f2bf(Wo[i - 196608]);
    } else if (i < 524288) {
        w2_b[i - 262144] = f2bf(W2[i - 262144]);
    } else if (i < 786432) {
        w3_b[i - 524288] = f2bf(W3[i - 524288]);
    } else {
        int j = i - 786432;                        // 0 .. 65535
        int spos = j >> 4, pi = j & 15;
        float inv_freq = powf(10000.0f, -(float)(2 * pi) / 32.0f);
        float fr = (float)spos * inv_freq;
        ct[j] = cosf(fr);
        st[j] = sinf(fr);
    }
}

// ---------------- LayerNorm: fp32 in, bf16 out ----------------
__global__ void ln_kernel(const float* __restrict__ x, const float* __restrict__ g,
                          const float* __restrict__ b, unsigned short* __restrict__ out) {
    __shared__ float red[8];
    int row = blockIdx.x;
    int tid = threadIdx.x;
    float v = x[(size_t)row * D + tid];
    float s = v, s2 = v * v;
    #pragma unroll
    for (int off = 32; off > 0; off >>= 1) {
        s  += __shfl_xor(s, off, 64);
        s2 += __shfl_xor(s2, off, 64);
    }
    int wave = tid >> 6;
    if ((tid & 63) == 0) { red[wave] = s; red[wave + 4] = s2; }
    __syncthreads();
    float sum   = red[0] + red[1] + red[2] + red[3];
    float sumsq = red[4] + red[5] + red[6] + red[7];
    float mu  = sum * (1.0f / D);
    float var = sumsq * (1.0f / D) - mu * mu;
    float rs  = rsqrtf(var + 1e-5f);
    out[(size_t)row * D + tid] = f2bf((v - mu) * rs * g[tid] + b[tid]);
}

// ------- bf16 MFMA GEMM, 64x64 tile, double-buffered, swizzled LDS -------
// modes: 0 = QKV: RoPE+store bf16 for cols<512 (Q cols<256 pre-scaled), cols>=512
//            stored TRANSPOSED to vt[B][H][DH][S]
//        1 = fp32 store acc+res; 2 = bf16 store gelu(acc+bias); 3 = fp32 store acc+bias+res
__global__ __launch_bounds__(256) void gemm64(const unsigned short* __restrict__ A,
        const unsigned short* __restrict__ Bw, void* __restrict__ outp,
        unsigned short* __restrict__ vt,
        const float* __restrict__ bias, const float* __restrict__ res,
        const float* __restrict__ ct, const float* __restrict__ st,
        int N, int K, int mode) {
    __shared__ unsigned short As[2][64 * 32];
    __shared__ unsigned short Bs[2][64 * 32];
    int tid = threadIdx.x;
    int w = tid >> 6, l = tid & 63;
    int lm = l & 15, lg = l >> 4;
    int wm = (w >> 1) * 32, wn = (w & 1) * 32;
    int bm = blockIdx.x * 64, bn = blockIdx.y * 64;
    // staging: lane l covers LDS row w*16+(l>>2), chunk l&3; fetch global chunk
    // XOR-swizzled by (row>>1)&3 = (l>>3)&3 so fragment reads are conflict-free
    const unsigned short* Ag = A + (size_t)(bm + w * 16 + (l >> 2)) * K + ((l & 3) ^ ((l >> 3) & 3)) * 8;
    const unsigned short* Bg = Bw + (size_t)(bn + w * 16 + (l >> 2)) * K + ((l & 3) ^ ((l >> 3) & 3)) * 8;
    const int kswz = (lm >> 1) & 3;
    f32x4 acc[2][2] = {};

    gload16(Ag, &As[0][w * 512]);
    gload16(Bg, &Bs[0][w * 512]);
    #pragma unroll 2
    for (int k0 = 0; k0 < K; k0 += 32) {
        int cur = (k0 >> 5) & 1;
        __syncthreads();
        if (k0 + 32 < K) {
            gload16(Ag + k0 + 32, &As[1 - cur][w * 512]);
            gload16(Bg + k0 + 32, &Bs[1 - cur][w * 512]);
        }
        short8 af[2], bf[2];
        #pragma unroll
        for (int i = 0; i < 2; ++i) af[i] = *(const short8*)&As[cur][(wm + i * 16 + lm) * 32 + (lg ^ kswz) * 8];
        #pragma unroll
        for (int i = 0; i < 2; ++i) bf[i] = *(const short8*)&Bs[cur][(wn + i * 16 + lm) * 32 + (lg ^ kswz) * 8];
        #pragma unroll
        for (int mi = 0; mi < 2; ++mi)
            #pragma unroll
            for (int ni = 0; ni < 2; ++ni)
                acc[mi][ni] = __builtin_amdgcn_mfma_f32_16x16x32_bf16(af[mi], bf[ni], acc[mi][ni], 0, 0, 0);
    }

    if (mode == 0) {
        if (bn >= 512) {
            // V part: store transposed to vt[B][H][DH][S]
            #pragma unroll
            for (int mi = 0; mi < 2; ++mi) {
                #pragma unroll
                for (int ni = 0; ni < 2; ++ni) {
                    int ng = bn + wn + ni * 16 + lm - 512;   // h*32+dh
                    int hh = ng >> 5, dh = ng & 31;
                    int mg0 = bm + wm + mi * 16 + lg * 4;
                    int bb = mg0 >> 12, ss = mg0 & 4095;
                    ushort4 pv;
                    pv.x = f2bf(acc[mi][ni][0]); pv.y = f2bf(acc[mi][ni][1]);
                    pv.z = f2bf(acc[mi][ni][2]); pv.w = f2bf(acc[mi][ni][3]);
                    *(ushort4*)(vt + ((size_t)((bb * 8 + hh) * 32 + dh)) * S + ss) = pv;
                }
            }
        } else {
            // RoPE on q/k columns (wave-uniform branch; shuffles are safe)
            #pragma unroll
            for (int mi = 0; mi < 2; ++mi) {
                #pragma unroll
                for (int ni = 0; ni < 2; ++ni) {
                    int ng = bn + wn + ni * 16 + lm;
                    int pi = (ng & 31) >> 1;
                    float sgn = (ng & 1) ? 1.f : -1.f;
                    float qs  = (ng < 256) ? QSCALE : 1.f;
                    #pragma unroll
                    for (int r2 = 0; r2 < 4; ++r2) {
                        int mg = bm + wm + mi * 16 + lg * 4 + r2;
                        int spos = mg & (S - 1);
                        float vv = acc[mi][ni][r2];
                        float pv = __shfl_xor(vv, 1, 64);
                        float cs = ct[spos * 16 + pi];
                        float sn = st[spos * 16 + pi];
                        float ov = (vv * cs + sgn * pv * sn) * qs;
                        ((unsigned short*)outp)[(size_t)mg * N + ng] = f2bf(ov);
                    }
                }
            }
        }
        return;
    }
    #pragma unroll
    for (int mi = 0; mi < 2; ++mi) {
        #pragma unroll
        for (int ni = 0; ni < 2; ++ni) {
            int ng = bn + wn + ni * 16 + lm;
            #pragma unroll
            for (int r2 = 0; r2 < 4; ++r2) {
                int mg = bm + wm + mi * 16 + lg * 4 + r2;
                float v = acc[mi][ni][r2];
                size_t idx = (size_t)mg * N + ng;
                if (mode == 1) {
                    ((float*)outp)[idx] = v + res[idx];
                } else if (mode == 2) {
                    float t = v + bias[ng];
                    ((unsigned short*)outp)[idx] = f2bf(0.5f * t * (1.0f + erff(t * 0.70710678118654752f)));
                } else {
                    ((float*)outp)[idx] = v + bias[ng] + res[idx];
                }
            }
        }
    }
}

// -------- MFMA flash attention: registers-only P via phi-permuted K staging --------
// K rows staged in permuted order phi(p) = 32*(p>>5) + 8*((p&15)>>2) + 4*((p>>4)&1) + (p&3)
// so lane (lm,lg)'s QK^T regs hold keys 8lg..8lg+7 for q=lm — exactly the PV B-operand
// fragment. P = exp2(scores) packs in-register; no LDS round trip. Softmax denominator
// rides the PV MFMA via a constant ones-row tile. Double-buffered K/V staging, XOR
// bank swizzles (verified conflict-free in R5). block = 4 waves x 16 q; grid = 1024.
__global__ __launch_bounds__(256) void attn_kernel(const unsigned short* __restrict__ Cq,
        const unsigned short* __restrict__ vt, unsigned short* __restrict__ out) {
    __shared__ unsigned short Ks[2][64][32];     // [buf][phys key row][dim]  (swizzled chunks)
    __shared__ unsigned short Vs[2][32][64];     // [buf][dim][key]           (swizzled chunks)
    __shared__ unsigned short Ones[16][64];      // row 0 = 1.0bf16, rest 0
    int tid = threadIdx.x;
    int w = tid >> 6, l = tid & 63;
    int lm = l & 15, lg = l >> 4;
    int qt = blockIdx.x & 63;
    int bh = blockIdx.x >> 6;
    int b = bh >> 3, h = bh & 7;
    int q0 = qt * 64 + w * 16;

    {   // ones tile init (16x64 ushorts = 256 lanes x 4)
        unsigned short val = (tid < 16) ? (unsigned short)0x3F80 : (unsigned short)0;
        *(ushort4*)(&Ones[0][0] + tid * 4) = make_ushort4(val, val, val, val);
    }

    const short8 qf = *(const short8*)(Cq + ((size_t)(b * S + q0 + lm)) * 768 + h * DH + lg * 8);
    // phi-permuted K staging: phys row p <- global key row phi(p)
    int p = w * 16 + (l >> 2);
    int krow = ((p >> 5) << 5) + (((p >> 2) & 3) << 3) + (((p >> 4) & 1) << 2) + (p & 3);
    const unsigned short* kg = Cq + ((size_t)(b * S)) * 768 + 256 + h * 32
                               + (size_t)krow * 768 + ((l & 3) ^ ((l >> 3) & 3)) * 8;
    const unsigned short* vg = vt + ((size_t)(bh * 32 + w * 8 + (l >> 3))) * S + ((l & 7) ^ (l >> 3)) * 8;
    const int kswz = (lm >> 1) & 3;
    const int vswz = lm & 7;

    f32x4 o0 = {0.f, 0.f, 0.f, 0.f}, o1 = {0.f, 0.f, 0.f, 0.f}, o2 = {0.f, 0.f, 0.f, 0.f};
    const f32x4 z = {0.f, 0.f, 0.f, 0.f};

    // prefetch tile 0 into buffer 0
    gload16(kg, &Ks[0][w * 16][0]);
    gload16(vg, &Vs[0][w * 8][0]);

    #pragma unroll 2
    for (int it = 0; it < S / 64; ++it) {
        int cur = it & 1;
        __syncthreads();   // drains prefetch of tile it; orders reads of buf[1-cur] from it-1
        if (it + 1 < S / 64) {
            gload16(kg + (size_t)(it + 1) * 64 * 768, &Ks[1 - cur][w * 16][0]);
            gload16(vg + (size_t)(it + 1) * 64,       &Vs[1 - cur][w * 8][0]);
        }
        #pragma unroll
        for (int half = 0; half < 2; ++half) {
            short8 kf0 = *(const short8*)&Ks[cur][half * 32 + lm][(lg ^ kswz) * 8];
            short8 kf1 = *(const short8*)&Ks[cur][half * 32 + 16 + lm][(lg ^ kswz) * 8];
            f32x4 s0 = __builtin_amdgcn_mfma_f32_16x16x32_bf16(kf0, qf, z, 0, 0, 0);
            f32x4 s1 = __builtin_amdgcn_mfma_f32_16x16x32_bf16(kf1, qf, z, 0, 0, 0);
            // lane (lm,lg): s0 = P-pre[q=lm][keys 8lg..+3], s1 = keys 8lg+4..+7
            unsigned u0[4], u1[4];
            #pragma unroll
            for (int i = 0; i < 4; ++i) {
                union { float f; unsigned u; } c0, c1;
                c0.f = __builtin_amdgcn_exp2f(s0[i]);
                c1.f = __builtin_amdgcn_exp2f(s1[i]);
                u0[i] = c0.u;   // truncate to bf16 (bias cancels num/denom)
                u1[i] = c1.u;
            }
            union { unsigned u[4]; short8 s; } pk;
            pk.u[0] = __builtin_amdgcn_perm(u0[1], u0[0], 0x07060302u);
            pk.u[1] = __builtin_amdgcn_perm(u0[3], u0[2], 0x07060302u);
            pk.u[2] = __builtin_amdgcn_perm(u1[1], u1[0], 0x07060302u);
            pk.u[3] = __builtin_amdgcn_perm(u1[3], u1[2], 0x07060302u);
            short8 pf = pk.s;   // B-operand fragment: keys 8lg..8lg+7, q=lm
            int vc = ((half * 4 + lg) ^ vswz) * 8;
            short8 va0 = *(const short8*)&Vs[cur][lm][vc];
            short8 va1 = *(const short8*)&Vs[cur][16 + lm][vc];
            short8 va2 = *(const short8*)&Ones[lm][vc];
            o0 = __builtin_amdgcn_mfma_f32_16x16x32_bf16(va0, pf, o0, 0, 0, 0);
            o1 = __builtin_amdgcn_mfma_f32_16x16x32_bf16(va1, pf, o1, 0, 0, 0);
            o2 = __builtin_amdgcn_mfma_f32_16x16x32_bf16(va2, pf, o2, 0, 0, 0);
        }
    }
    // softmax denominator for q=lm sits in lane lm (lg=0, reg 0) of o2
    float lsum = __shfl(o2[0], lm, 64);
    float inv = 1.0f / lsum;
    ushort4 r0, r1;
    r0.x = f2bf(o0[0] * inv); r0.y = f2bf(o0[1] * inv);
    r0.z = f2bf(o0[2] * inv); r0.w = f2bf(o0[3] * inv);
    r1.x = f2bf(o1[0] * inv); r1.y = f2bf(o1[1] * inv);
    r1.z = f2bf(o1[2] * inv); r1.w = f2bf(o1[3] * inv);
    unsigned short* ob = out + ((size_t)(b * S + q0 + lm)) * D + h * DH;
    *(ushort4*)(ob + lg * 4)      = r0;
    *(ushort4*)(ob + 16 + lg * 4) = r1;
}

extern "C" void kernel_launch(void* const* d_in, const int* in_sizes, int n_in,
                              void* d_out, int out_size, void* d_ws, size_t ws_size,
                              hipStream_t stream) {
    const float* x     = (const float*)d_in[0];
    const float* Wq    = (const float*)d_in[1];
    const float* Wk    = (const float*)d_in[2];
    const float* Wv    = (const float*)d_in[3];
    const float* Wo    = (const float*)d_in[4];
    const float* ln1_g = (const float*)d_in[5];
    const float* ln1_b = (const float*)d_in[6];
    const float* ln2_g = (const float*)d_in[7];
    const float* ln2_b = (const float*)d_in[8];
    const float* W2    = (const float*)d_in[9];
    const float* b2    = (const float*)d_in[10];
    const float* W3    = (const float*)d_in[11];
    const float* b3    = (const float*)d_in[12];

    char* w8 = (char*)d_ws;
    unsigned short* wqkv = (unsigned short*)(w8);             // 196608 ush
    unsigned short* wo_b = (unsigned short*)(w8 + 393216);    // 65536
    unsigned short* w2_b = (unsigned short*)(w8 + 524288);    // 262144
    unsigned short* w3_b = (unsigned short*)(w8 + 1048576);   // 262144
    float*          ct   = (float*)(w8 + 1572864);            // 65536 f32
    float*          st   = (float*)(w8 + 1835008);            // 65536 f32
    unsigned short* xn   = (unsigned short*)(w8 + 2097152);   // 2M ush (reused as yn)
    unsigned short* Cq   = (unsigned short*)(w8 + 6291456);   // 6.29M ush (QKV out)
    unsigned short* hb   = Cq;                                // MLP hidden reuses (16MB)
    unsigned short* vtb  = (unsigned short*)(w8 + 23068672);  // 2M ush
    unsigned short* ab   = (unsigned short*)(w8 + 27262976);  // 2M ush
    float*          mlpin= (float*)(w8 + 31457280);           // 2M f32
    unsigned short* yn   = xn;

    conv_all<<<3328, 256, 0, stream>>>(Wq, Wk, Wv, Wo, W2, W3, wqkv, wo_b, w2_b, w3_b, ct, st);
    ln_kernel<<<NTOK, 256, 0, stream>>>(x, ln1_g, ln1_b, xn);
    gemm64<<<dim3(128, 12), 256, 0, stream>>>(xn, wqkv, Cq, vtb, nullptr, nullptr, ct, st, 768, 256, 0);
    attn_kernel<<<1024, 256, 0, stream>>>(Cq, vtb, ab);
    gemm64<<<dim3(128, 4), 256, 0, stream>>>(ab, wo_b, mlpin, nullptr, nullptr, x, nullptr, nullptr, 256, 256, 1);
    ln_kernel<<<NTOK, 256, 0, stream>>>(mlpin, ln2_g, ln2_b, yn);
    gemm64<<<dim3(128, 16), 256, 0, stream>>>(yn, w2_b, hb, nullptr, b2, nullptr, nullptr, nullptr, 1024, 256, 2);
    gemm64<<<dim3(128, 4), 256, 0, stream>>>(hb, w3_b, (float*)d_out, nullptr, b3, mlpin, nullptr, nullptr, 256, 1024, 3);
}

// Round 7
// 209.552 us; speedup vs baseline: 30.4857x; 1.0459x over previous
//
#include <hip/hip_runtime.h>
#include <math.h>

#define D 256
#define S 4096
#define H 8
#define DH 32
#define DM 1024
#define NTOK 8192   // B*S

typedef __attribute__((ext_vector_type(8))) short short8;
typedef __attribute__((ext_vector_type(4))) float f32x4;

// qscale = (1/sqrt(32)) * log2(e): folds softmax scale + exp->exp2 into Q
#define QSCALE (0.17677669529663687f * 1.4426950408889634f)

__device__ inline unsigned short f2bf(float f) {
    union { float f; unsigned u; } v; v.f = f;
    unsigned r = v.u + 0x7fffu + ((v.u >> 16) & 1u);
    return (unsigned short)(r >> 16);
}
__device__ inline void gload16(const void* g, void* l) {
    __builtin_amdgcn_global_load_lds((const __attribute__((address_space(1))) void*)g,
                                     (__attribute__((address_space(3))) void*)l, 16, 0, 0);
}

// -------- fp32 -> bf16 weights + RoPE cos/sin table, one launch --------
__global__ void conv_all(const float* __restrict__ Wq, const float* __restrict__ Wk,
                         const float* __restrict__ Wv, const float* __restrict__ Wo,
                         const float* __restrict__ W2, const float* __restrict__ W3,
                         unsigned short* __restrict__ wqkv, unsigned short* __restrict__ wo_b,
                         unsigned short* __restrict__ w2_b, unsigned short* __restrict__ w3_b,
                         float* __restrict__ ct, float* __restrict__ st) {
    int i = blockIdx.x * 256 + threadIdx.x;       // 0 .. 851967
    if (i < 196608) {
        const float* s = (i < 65536) ? Wq : ((i < 131072) ? Wk : Wv);
        wqkv[i] = f2bf(s[i & 65535]);
    } else if (i < 262144) {
        wo_b[i - 196608] = f2bf(Wo[i - 196608]);
    } else if (i < 524288) {
        w2_b[i - 262144] = f2bf(W2[i - 262144]);
    } else if (i < 786432) {
        w3_b[i - 524288] = f2bf(W3[i - 524288]);
    } else {
        int j = i - 786432;                        // 0 .. 65535
        int spos = j >> 4, pi = j & 15;
        float inv_freq = powf(10000.0f, -(float)(2 * pi) / 32.0f);
        float fr = (float)spos * inv_freq;
        ct[j] = cosf(fr);
        st[j] = sinf(fr);
    }
}

// ---------------- LayerNorm: fp32 in, bf16 out ----------------
__global__ void ln_kernel(const float* __restrict__ x, const float* __restrict__ g,
                          const float* __restrict__ b, unsigned short* __restrict__ out) {
    __shared__ float red[8];
    int row = blockIdx.x;
    int tid = threadIdx.x;
    float v = x[(size_t)row * D + tid];
    float s = v, s2 = v * v;
    #pragma unroll
    for (int off = 32; off > 0; off >>= 1) {
        s  += __shfl_xor(s, off, 64);
        s2 += __shfl_xor(s2, off, 64);
    }
    int wave = tid >> 6;
    if ((tid & 63) == 0) { red[wave] = s; red[wave + 4] = s2; }
    __syncthreads();
    float sum   = red[0] + red[1] + red[2] + red[3];
    float sumsq = red[4] + red[5] + red[6] + red[7];
    float mu  = sum * (1.0f / D);
    float var = sumsq * (1.0f / D) - mu * mu;
    float rs  = rsqrtf(var + 1e-5f);
    out[(size_t)row * D + tid] = f2bf((v - mu) * rs * g[tid] + b[tid]);
}

// ------- bf16 MFMA GEMM, 128x64 block tile (wave = 64x32), dbuf, swizzled -------
// modes: 0 = QKV: RoPE+store bf16 for cols<512 (Q cols<256 pre-scaled), cols>=512
//            stored TRANSPOSED to vt[B][H][DH][S]
//        1 = fp32 store acc+res; 2 = bf16 store gelu(acc+bias); 3 = fp32 store acc+bias+res
__global__ __launch_bounds__(256) void gemm128(const unsigned short* __restrict__ A,
        const unsigned short* __restrict__ Bw, void* __restrict__ outp,
        unsigned short* __restrict__ vt,
        const float* __restrict__ bias, const float* __restrict__ res,
        const float* __restrict__ ct, const float* __restrict__ st,
        int N, int K, int mode) {
    __shared__ unsigned short As[2][128 * 32];
    __shared__ unsigned short Bs[2][64 * 32];
    int tid = threadIdx.x;
    int w = tid >> 6, l = tid & 63;
    int lm = l & 15, lg = l >> 4;
    int wm = (w >> 1) * 64, wn = (w & 1) * 32;
    int bm = blockIdx.x * 128, bn = blockIdx.y * 64;
    // staging lane->row w*16+(l>>2), chunk l&3; global chunk XOR-swizzled by (row>>1)&3
    const unsigned short* Ag = A + (size_t)(bm + w * 16 + (l >> 2)) * K + ((l & 3) ^ ((l >> 3) & 3)) * 8;
    const unsigned short* Bg = Bw + (size_t)(bn + w * 16 + (l >> 2)) * K + ((l & 3) ^ ((l >> 3) & 3)) * 8;
    const int kswz = (lm >> 1) & 3;
    f32x4 acc[4][2] = {};

    gload16(Ag, &As[0][w * 512]);
    gload16(Ag + (size_t)64 * K, &As[0][2048 + w * 512]);
    gload16(Bg, &Bs[0][w * 512]);
    #pragma unroll 2
    for (int k0 = 0; k0 < K; k0 += 32) {
        int cur = (k0 >> 5) & 1;
        __syncthreads();
        if (k0 + 32 < K) {
            gload16(Ag + k0 + 32, &As[1 - cur][w * 512]);
            gload16(Ag + (size_t)64 * K + k0 + 32, &As[1 - cur][2048 + w * 512]);
            gload16(Bg + k0 + 32, &Bs[1 - cur][w * 512]);
        }
        short8 af[4], bf[2];
        #pragma unroll
        for (int i = 0; i < 4; ++i) af[i] = *(const short8*)&As[cur][(wm + i * 16 + lm) * 32 + (lg ^ kswz) * 8];
        #pragma unroll
        for (int i = 0; i < 2; ++i) bf[i] = *(const short8*)&Bs[cur][(wn + i * 16 + lm) * 32 + (lg ^ kswz) * 8];
        #pragma unroll
        for (int mi = 0; mi < 4; ++mi)
            #pragma unroll
            for (int ni = 0; ni < 2; ++ni)
                acc[mi][ni] = __builtin_amdgcn_mfma_f32_16x16x32_bf16(af[mi], bf[ni], acc[mi][ni], 0, 0, 0);
    }

    if (mode == 0) {
        if (bn >= 512) {
            // V part: store transposed to vt[B][H][DH][S]
            #pragma unroll
            for (int mi = 0; mi < 4; ++mi) {
                #pragma unroll
                for (int ni = 0; ni < 2; ++ni) {
                    int ng = bn + wn + ni * 16 + lm - 512;   // h*32+dh
                    int hh = ng >> 5, dh = ng & 31;
                    int mg0 = bm + wm + mi * 16 + lg * 4;
                    int bb = mg0 >> 12, ss = mg0 & 4095;
                    ushort4 pv;
                    pv.x = f2bf(acc[mi][ni][0]); pv.y = f2bf(acc[mi][ni][1]);
                    pv.z = f2bf(acc[mi][ni][2]); pv.w = f2bf(acc[mi][ni][3]);
                    *(ushort4*)(vt + ((size_t)((bb * 8 + hh) * 32 + dh)) * S + ss) = pv;
                }
            }
        } else {
            // RoPE on q/k columns (wave-uniform branch; shuffles are safe)
            #pragma unroll
            for (int mi = 0; mi < 4; ++mi) {
                #pragma unroll
                for (int ni = 0; ni < 2; ++ni) {
                    int ng = bn + wn + ni * 16 + lm;
                    int pi = (ng & 31) >> 1;
                    float sgn = (ng & 1) ? 1.f : -1.f;
                    float qs  = (ng < 256) ? QSCALE : 1.f;
                    #pragma unroll
                    for (int r2 = 0; r2 < 4; ++r2) {
                        int mg = bm + wm + mi * 16 + lg * 4 + r2;
                        int spos = mg & (S - 1);
                        float vv = acc[mi][ni][r2];
                        float pv = __shfl_xor(vv, 1, 64);
                        float cs = ct[spos * 16 + pi];
                        float sn = st[spos * 16 + pi];
                        float ov = (vv * cs + sgn * pv * sn) * qs;
                        ((unsigned short*)outp)[(size_t)mg * N + ng] = f2bf(ov);
                    }
                }
            }
        }
        return;
    }
    #pragma unroll
    for (int mi = 0; mi < 4; ++mi) {
        #pragma unroll
        for (int ni = 0; ni < 2; ++ni) {
            int ng = bn + wn + ni * 16 + lm;
            #pragma unroll
            for (int r2 = 0; r2 < 4; ++r2) {
                int mg = bm + wm + mi * 16 + lg * 4 + r2;
                float v = acc[mi][ni][r2];
                size_t idx = (size_t)mg * N + ng;
                if (mode == 1) {
                    ((float*)outp)[idx] = v + res[idx];
                } else if (mode == 2) {
                    float t = v + bias[ng];
                    ((unsigned short*)outp)[idx] = f2bf(0.5f * t * (1.0f + erff(t * 0.70710678118654752f)));
                } else {
                    ((float*)outp)[idx] = v + bias[ng] + res[idx];
                }
            }
        }
    }
}

// -------- MFMA flash attention: registers-only P, 8 waves / 128 q rows / block ----
// K rows staged phi-permuted (phi(p) = 32*(p>>5) + 8*((p&15)>>2) + 4*((p>>4)&1) + (p&3))
// so lane (lm,lg)'s QK^T regs are exactly the PV B-operand fragment; P = exp2(scores)
// packs in-register (no LDS round trip). Denominator rides PV MFMA via ones-row tile.
// Waves 0-3 stage K, waves 4-7 stage V (halved staging work/wave, 2x tile reuse).
// grid = B*H*(S/128) = 512 = 2 blocks/CU x 8 waves = 16 waves/CU.
__global__ __launch_bounds__(512) void attn_kernel(const unsigned short* __restrict__ Cq,
        const unsigned short* __restrict__ vt, unsigned short* __restrict__ out) {
    __shared__ unsigned short Ks[2][64][32];     // [buf][phys key row][dim]  (swizzled chunks)
    __shared__ unsigned short Vs[2][32][64];     // [buf][dim][key]           (swizzled chunks)
    __shared__ unsigned short Ones[16][64];      // row 0 = 1.0bf16, rest 0
    int tid = threadIdx.x;
    int w = tid >> 6, l = tid & 63;
    int lm = l & 15, lg = l >> 4;
    int qt = blockIdx.x & 31;
    int bh = blockIdx.x >> 5;
    int b = bh >> 3, h = bh & 7;
    int q0 = qt * 128 + w * 16;

    if (tid < 256) {   // ones tile init (16x64 ushorts = 256 lanes x 4)
        unsigned short val = (tid < 16) ? (unsigned short)0x3F80 : (unsigned short)0;
        *(ushort4*)(&Ones[0][0] + tid * 4) = make_ushort4(val, val, val, val);
    }

    const short8 qf = *(const short8*)(Cq + ((size_t)(b * S + q0 + lm)) * 768 + h * DH + lg * 8);
    // staging addresses: waves 0-3 stage K (phi-permuted rows), waves 4-7 stage V
    int ws = w & 3;
    int p = ws * 16 + (l >> 2);
    int krow = ((p >> 5) << 5) + (((p >> 2) & 3) << 3) + (((p >> 4) & 1) << 2) + (p & 3);
    const unsigned short* kg = Cq + ((size_t)(b * S)) * 768 + 256 + h * 32
                               + (size_t)krow * 768 + ((l & 3) ^ ((l >> 3) & 3)) * 8;
    const unsigned short* vg = vt + ((size_t)(bh * 32 + ws * 8 + (l >> 3))) * S + ((l & 7) ^ (l >> 3)) * 8;
    unsigned short* klds0 = &Ks[0][ws * 16][0];
    unsigned short* vlds0 = &Vs[0][ws * 8][0];
    unsigned short* klds1 = &Ks[1][ws * 16][0];
    unsigned short* vlds1 = &Vs[1][ws * 8][0];
    const int kswz = (lm >> 1) & 3;
    const int vswz = lm & 7;

    f32x4 o0 = {0.f, 0.f, 0.f, 0.f}, o1 = {0.f, 0.f, 0.f, 0.f}, o2 = {0.f, 0.f, 0.f, 0.f};
    const f32x4 z = {0.f, 0.f, 0.f, 0.f};

    // prefetch tile 0 into buffer 0
    if (w < 4) gload16(kg, klds0);
    else       gload16(vg, vlds0);

    #pragma unroll 2
    for (int it = 0; it < S / 64; ++it) {
        int cur = it & 1;
        __syncthreads();   // drains prefetch of tile it; orders reads of buf[1-cur] from it-1
        if (it + 1 < S / 64) {
            if (w < 4) gload16(kg + (size_t)(it + 1) * 64 * 768, cur ? klds0 : klds1);
            else       gload16(vg + (size_t)(it + 1) * 64,       cur ? vlds0 : vlds1);
        }
        #pragma unroll
        for (int half = 0; half < 2; ++half) {
            short8 kf0 = *(const short8*)&Ks[cur][half * 32 + lm][(lg ^ kswz) * 8];
            short8 kf1 = *(const short8*)&Ks[cur][half * 32 + 16 + lm][(lg ^ kswz) * 8];
            f32x4 s0 = __builtin_amdgcn_mfma_f32_16x16x32_bf16(kf0, qf, z, 0, 0, 0);
            f32x4 s1 = __builtin_amdgcn_mfma_f32_16x16x32_bf16(kf1, qf, z, 0, 0, 0);
            // lane (lm,lg): s0 = P-pre[q=lm][keys 8lg..+3], s1 = keys 8lg+4..+7
            unsigned u0[4], u1[4];
            #pragma unroll
            for (int i = 0; i < 4; ++i) {
                union { float f; unsigned u; } c0, c1;
                c0.f = __builtin_amdgcn_exp2f(s0[i]);
                c1.f = __builtin_amdgcn_exp2f(s1[i]);
                u0[i] = c0.u;   // truncate to bf16 (bias cancels num/denom)
                u1[i] = c1.u;
            }
            union { unsigned u[4]; short8 s; } pk;
            pk.u[0] = __builtin_amdgcn_perm(u0[1], u0[0], 0x07060302u);
            pk.u[1] = __builtin_amdgcn_perm(u0[3], u0[2], 0x07060302u);
            pk.u[2] = __builtin_amdgcn_perm(u1[1], u1[0], 0x07060302u);
            pk.u[3] = __builtin_amdgcn_perm(u1[3], u1[2], 0x07060302u);
            short8 pf = pk.s;   // B-operand fragment: keys 8lg..8lg+7, q=lm
            int vc = ((half * 4 + lg) ^ vswz) * 8;
            short8 va0 = *(const short8*)&Vs[cur][lm][vc];
            short8 va1 = *(const short8*)&Vs[cur][16 + lm][vc];
            short8 va2 = *(const short8*)&Ones[lm][vc];
            o0 = __builtin_amdgcn_mfma_f32_16x16x32_bf16(va0, pf, o0, 0, 0, 0);
            o1 = __builtin_amdgcn_mfma_f32_16x16x32_bf16(va1, pf, o1, 0, 0, 0);
            o2 = __builtin_amdgcn_mfma_f32_16x16x32_bf16(va2, pf, o2, 0, 0, 0);
        }
    }
    // softmax denominator for q=lm sits in lane lm (lg=0, reg 0) of o2
    float lsum = __shfl(o2[0], lm, 64);
    float inv = 1.0f / lsum;
    ushort4 r0, r1;
    r0.x = f2bf(o0[0] * inv); r0.y = f2bf(o0[1] * inv);
    r0.z = f2bf(o0[2] * inv); r0.w = f2bf(o0[3] * inv);
    r1.x = f2bf(o1[0] * inv); r1.y = f2bf(o1[1] * inv);
    r1.z = f2bf(o1[2] * inv); r1.w = f2bf(o1[3] * inv);
    unsigned short* ob = out + ((size_t)(b * S + q0 + lm)) * D + h * DH;
    *(ushort4*)(ob + lg * 4)      = r0;
    *(ushort4*)(ob + 16 + lg * 4) = r1;
}

extern "C" void kernel_launch(void* const* d_in, const int* in_sizes, int n_in,
                              void* d_out, int out_size, void* d_ws, size_t ws_size,
                              hipStream_t stream) {
    const float* x     = (const float*)d_in[0];
    const float* Wq    = (const float*)d_in[1];
    const float* Wk    = (const float*)d_in[2];
    const float* Wv    = (const float*)d_in[3];
    const float* Wo    = (const float*)d_in[4];
    const float* ln1_g = (const float*)d_in[5];
    const float* ln1_b = (const float*)d_in[6];
    const float* ln2_g = (const float*)d_in[7];
    const float* ln2_b = (const float*)d_in[8];
    const float* W2    = (const float*)d_in[9];
    const float* b2    = (const float*)d_in[10];
    const float* W3    = (const float*)d_in[11];
    const float* b3    = (const float*)d_in[12];

    char* w8 = (char*)d_ws;
    unsigned short* wqkv = (unsigned short*)(w8);             // 196608 ush
    unsigned short* wo_b = (unsigned short*)(w8 + 393216);    // 65536
    unsigned short* w2_b = (unsigned short*)(w8 + 524288);    // 262144
    unsigned short* w3_b = (unsigned short*)(w8 + 1048576);   // 262144
    float*          ct   = (float*)(w8 + 1572864);            // 65536 f32
    float*          st   = (float*)(w8 + 1835008);            // 65536 f32
    unsigned short* xn   = (unsigned short*)(w8 + 2097152);   // 2M ush (reused as yn)
    unsigned short* Cq   = (unsigned short*)(w8 + 6291456);   // 6.29M ush (QKV out)
    unsigned short* hb   = Cq;                                // MLP hidden reuses (16MB)
    unsigned short* vtb  = (unsigned short*)(w8 + 23068672);  // 2M ush
    unsigned short* ab   = (unsigned short*)(w8 + 27262976);  // 2M ush
    float*          mlpin= (float*)(w8 + 31457280);           // 2M f32
    unsigned short* yn   = xn;

    conv_all<<<3328, 256, 0, stream>>>(Wq, Wk, Wv, Wo, W2, W3, wqkv, wo_b, w2_b, w3_b, ct, st);
    ln_kernel<<<NTOK, 256, 0, stream>>>(x, ln1_g, ln1_b, xn);
    gemm128<<<dim3(64, 12), 256, 0, stream>>>(xn, wqkv, Cq, vtb, nullptr, nullptr, ct, st, 768, 256, 0);
    attn_kernel<<<512, 512, 0, stream>>>(Cq, vtb, ab);
    gemm128<<<dim3(64, 4), 256, 0, stream>>>(ab, wo_b, mlpin, nullptr, nullptr, x, nullptr, nullptr, 256, 256, 1);
    ln_kernel<<<NTOK, 256, 0, stream>>>(mlpin, ln2_g, ln2_b, yn);
    gemm128<<<dim3(64, 16), 256, 0, stream>>>(yn, w2_b, hb, nullptr, b2, nullptr, nullptr, nullptr, 1024, 256, 2);
    gemm128<<<dim3(64, 4), 256, 0, stream>>>(hb, w3_b, (float*)d_out, nullptr, b3, mlpin, nullptr, nullptr, 256, 1024, 3);
}

// Round 8
// 206.152 us; speedup vs baseline: 30.9885x; 1.0165x over previous
//
#include <hip/hip_runtime.h>
#include <math.h>

#define D 256
#define S 4096
#define H 8
#define DH 32
#define DM 1024
#define NTOK 8192   // B*S

typedef __attribute__((ext_vector_type(8))) short short8;
typedef __attribute__((ext_vector_type(4))) float f32x4;

// qscale = (1/sqrt(32)) * log2(e): folds softmax scale + exp->exp2 into Q
#define QSCALE (0.17677669529663687f * 1.4426950408889634f)

__device__ inline unsigned short f2bf(float f) {
    union { float f; unsigned u; } v; v.f = f;
    unsigned r = v.u + 0x7fffu + ((v.u >> 16) & 1u);
    return (unsigned short)(r >> 16);
}
__device__ inline void gload16(const void* g, void* l) {
    __builtin_amdgcn_global_load_lds((const __attribute__((address_space(1))) void*)g,
                                     (__attribute__((address_space(3))) void*)l, 16, 0, 0);
}

// -------- fp32 -> bf16 weights + RoPE cos/sin table, one launch --------
__global__ void conv_all(const float* __restrict__ Wq, const float* __restrict__ Wk,
                         const float* __restrict__ Wv, const float* __restrict__ Wo,
                         const float* __restrict__ W2, const float* __restrict__ W3,
                         unsigned short* __restrict__ wqkv, unsigned short* __restrict__ wo_b,
                         unsigned short* __restrict__ w2_b, unsigned short* __restrict__ w3_b,
                         float* __restrict__ ct, float* __restrict__ st) {
    int i = blockIdx.x * 256 + threadIdx.x;       // 0 .. 851967
    if (i < 196608) {
        const float* s = (i < 65536) ? Wq : ((i < 131072) ? Wk : Wv);
        wqkv[i] = f2bf(s[i & 65535]);
    } else if (i < 262144) {
        wo_b[i - 196608] = f2bf(Wo[i - 196608]);
    } else if (i < 524288) {
        w2_b[i - 262144] = f2bf(W2[i - 262144]);
    } else if (i < 786432) {
        w3_b[i - 524288] = f2bf(W3[i - 524288]);
    } else {
        int j = i - 786432;                        // 0 .. 65535
        int spos = j >> 4, pi = j & 15;
        float inv_freq = powf(10000.0f, -(float)(2 * pi) / 32.0f);
        float fr = (float)spos * inv_freq;
        ct[j] = cosf(fr);
        st[j] = sinf(fr);
    }
}

// ---------------- LayerNorm: fp32 in, bf16 out ----------------
__global__ void ln_kernel(const float* __restrict__ x, const float* __restrict__ g,
                          const float* __restrict__ b, unsigned short* __restrict__ out) {
    __shared__ float red[8];
    int row = blockIdx.x;
    int tid = threadIdx.x;
    float v = x[(size_t)row * D + tid];
    float s = v, s2 = v * v;
    #pragma unroll
    for (int off = 32; off > 0; off >>= 1) {
        s  += __shfl_xor(s, off, 64);
        s2 += __shfl_xor(s2, off, 64);
    }
    int wave = tid >> 6;
    if ((tid & 63) == 0) { red[wave] = s; red[wave + 4] = s2; }
    __syncthreads();
    float sum   = red[0] + red[1] + red[2] + red[3];
    float sumsq = red[4] + red[5] + red[6] + red[7];
    float mu  = sum * (1.0f / D);
    float var = sumsq * (1.0f / D) - mu * mu;
    float rs  = rsqrtf(var + 1e-5f);
    out[(size_t)row * D + tid] = f2bf((v - mu) * rs * g[tid] + b[tid]);
}

// ------- bf16 MFMA GEMM, 64x64 tile, FULL-K LDS staging (BK=256), 1 barrier/pass -------
// The entire A-tile (64xBK) and B-tile (64xBK) are staged in one burst of independent
// global_load_lds, then ONE barrier, then 32 back-to-back MFMAs with no intervening
// syncs. LDS row stride 512B, chunk XOR-swizzle c^(row&7): balanced 8-lanes-per-4-bank
// group per quarter-wave (same class as the R6-verified attention pattern, 0 conflicts).
// modes: 0 = QKV: RoPE+store bf16 for cols<512 (Q cols<256 pre-scaled), cols>=512
//            stored TRANSPOSED to vt[B][H][DH][S]
//        1 = fp32 store acc+res; 2 = bf16 store gelu(acc+bias); 3 = fp32 store acc+bias+res
__global__ __launch_bounds__(256) void gemm_fat(const unsigned short* __restrict__ A,
        const unsigned short* __restrict__ Bw, void* __restrict__ outp,
        unsigned short* __restrict__ vt,
        const float* __restrict__ bias, const float* __restrict__ res,
        const float* __restrict__ ct, const float* __restrict__ st,
        int N, int K, int mode) {
    __shared__ unsigned short As[64 * 256];
    __shared__ unsigned short Bs[64 * 256];
    int tid = threadIdx.x;
    int w = tid >> 6, l = tid & 63;
    int lm = l & 15, lg = l >> 4;
    int wm = (w >> 1) * 32, wn = (w & 1) * 32;
    int bm = blockIdx.x * 64, bn = blockIdx.y * 64;
    // staging: round it covers rows it*8+row0 (row0=tid>>5), 32 chunks/row (16B each);
    // global chunk = pc ^ (row&7); row&7 invariant across rounds (stride 8)
    int row0 = tid >> 5, pc = tid & 31;
    int pcx = (pc ^ (row0 & 7)) * 8;
    const int swz = lm & 7;
    f32x4 acc[2][2] = {};

    for (int kp = 0; kp < K; kp += 256) {
        if (kp) __syncthreads();
        const unsigned short* Ag = A + (size_t)(bm + row0) * K + kp + pcx;
        const unsigned short* Bg = Bw + (size_t)(bn + row0) * K + kp + pcx;
        unsigned short* al = &As[w * 512];
        unsigned short* bl = &Bs[w * 512];
        #pragma unroll
        for (int it = 0; it < 8; ++it) {
            gload16(Ag + (size_t)it * 8 * K, al + it * 2048);
            gload16(Bg + (size_t)it * 8 * K, bl + it * 2048);
        }
        __syncthreads();
        #pragma unroll
        for (int kk = 0; kk < 8; ++kk) {
            short8 af[2], bf[2];
            int ch = ((kk * 4 + lg) ^ swz) * 8;
            #pragma unroll
            for (int i = 0; i < 2; ++i) af[i] = *(const short8*)&As[(wm + i * 16 + lm) * 256 + ch];
            #pragma unroll
            for (int i = 0; i < 2; ++i) bf[i] = *(const short8*)&Bs[(wn + i * 16 + lm) * 256 + ch];
            #pragma unroll
            for (int mi = 0; mi < 2; ++mi)
                #pragma unroll
                for (int ni = 0; ni < 2; ++ni)
                    acc[mi][ni] = __builtin_amdgcn_mfma_f32_16x16x32_bf16(af[mi], bf[ni], acc[mi][ni], 0, 0, 0);
        }
    }

    if (mode == 0) {
        if (bn >= 512) {
            // V part: store transposed to vt[B][H][DH][S]
            #pragma unroll
            for (int mi = 0; mi < 2; ++mi) {
                #pragma unroll
                for (int ni = 0; ni < 2; ++ni) {
                    int ng = bn + wn + ni * 16 + lm - 512;   // h*32+dh
                    int hh = ng >> 5, dh = ng & 31;
                    int mg0 = bm + wm + mi * 16 + lg * 4;
                    int bb = mg0 >> 12, ss = mg0 & 4095;
                    ushort4 pv;
                    pv.x = f2bf(acc[mi][ni][0]); pv.y = f2bf(acc[mi][ni][1]);
                    pv.z = f2bf(acc[mi][ni][2]); pv.w = f2bf(acc[mi][ni][3]);
                    *(ushort4*)(vt + ((size_t)((bb * 8 + hh) * 32 + dh)) * S + ss) = pv;
                }
            }
        } else {
            // RoPE on q/k columns (wave-uniform branch; shuffles are safe)
            #pragma unroll
            for (int mi = 0; mi < 2; ++mi) {
                #pragma unroll
                for (int ni = 0; ni < 2; ++ni) {
                    int ng = bn + wn + ni * 16 + lm;
                    int pi = (ng & 31) >> 1;
                    float sgn = (ng & 1) ? 1.f : -1.f;
                    float qs  = (ng < 256) ? QSCALE : 1.f;
                    #pragma unroll
                    for (int r2 = 0; r2 < 4; ++r2) {
                        int mg = bm + wm + mi * 16 + lg * 4 + r2;
                        int spos = mg & (S - 1);
                        float vv = acc[mi][ni][r2];
                        float pv = __shfl_xor(vv, 1, 64);
                        float cs = ct[spos * 16 + pi];
                        float sn = st[spos * 16 + pi];
                        float ov = (vv * cs + sgn * pv * sn) * qs;
                        ((unsigned short*)outp)[(size_t)mg * N + ng] = f2bf(ov);
                    }
                }
            }
        }
        return;
    }
    #pragma unroll
    for (int mi = 0; mi < 2; ++mi) {
        #pragma unroll
        for (int ni = 0; ni < 2; ++ni) {
            int ng = bn + wn + ni * 16 + lm;
            #pragma unroll
            for (int r2 = 0; r2 < 4; ++r2) {
                int mg = bm + wm + mi * 16 + lg * 4 + r2;
                float v = acc[mi][ni][r2];
                size_t idx = (size_t)mg * N + ng;
                if (mode == 1) {
                    ((float*)outp)[idx] = v + res[idx];
                } else if (mode == 2) {
                    float t = v + bias[ng];
                    ((unsigned short*)outp)[idx] = f2bf(0.5f * t * (1.0f + erff(t * 0.70710678118654752f)));
                } else {
                    ((float*)outp)[idx] = v + bias[ng] + res[idx];
                }
            }
        }
    }
}

// -------- MFMA flash attention: registers-only P, 8 waves / 128 q rows / block ----
// K rows staged phi-permuted (phi(p) = 32*(p>>5) + 8*((p&15)>>2) + 4*((p>>4)&1) + (p&3))
// so lane (lm,lg)'s QK^T regs are exactly the PV B-operand fragment; P = exp2(scores)
// packs in-register (no LDS round trip). Denominator rides PV MFMA via ones-row tile.
// Waves 0-3 stage K, waves 4-7 stage V (halved staging work/wave, 2x tile reuse).
// grid = B*H*(S/128) = 512 = 2 blocks/CU x 8 waves = 16 waves/CU.
__global__ __launch_bounds__(512) void attn_kernel(const unsigned short* __restrict__ Cq,
        const unsigned short* __restrict__ vt, unsigned short* __restrict__ out) {
    __shared__ unsigned short Ks[2][64][32];     // [buf][phys key row][dim]  (swizzled chunks)
    __shared__ unsigned short Vs[2][32][64];     // [buf][dim][key]           (swizzled chunks)
    __shared__ unsigned short Ones[16][64];      // row 0 = 1.0bf16, rest 0
    int tid = threadIdx.x;
    int w = tid >> 6, l = tid & 63;
    int lm = l & 15, lg = l >> 4;
    int qt = blockIdx.x & 31;
    int bh = blockIdx.x >> 5;
    int b = bh >> 3, h = bh & 7;
    int q0 = qt * 128 + w * 16;

    if (tid < 256) {   // ones tile init (16x64 ushorts = 256 lanes x 4)
        unsigned short val = (tid < 16) ? (unsigned short)0x3F80 : (unsigned short)0;
        *(ushort4*)(&Ones[0][0] + tid * 4) = make_ushort4(val, val, val, val);
    }

    const short8 qf = *(const short8*)(Cq + ((size_t)(b * S + q0 + lm)) * 768 + h * DH + lg * 8);
    // staging addresses: waves 0-3 stage K (phi-permuted rows), waves 4-7 stage V
    int ws = w & 3;
    int p = ws * 16 + (l >> 2);
    int krow = ((p >> 5) << 5) + (((p >> 2) & 3) << 3) + (((p >> 4) & 1) << 2) + (p & 3);
    const unsigned short* kg = Cq + ((size_t)(b * S)) * 768 + 256 + h * 32
                               + (size_t)krow * 768 + ((l & 3) ^ ((l >> 3) & 3)) * 8;
    const unsigned short* vg = vt + ((size_t)(bh * 32 + ws * 8 + (l >> 3))) * S + ((l & 7) ^ (l >> 3)) * 8;
    unsigned short* klds0 = &Ks[0][ws * 16][0];
    unsigned short* vlds0 = &Vs[0][ws * 8][0];
    unsigned short* klds1 = &Ks[1][ws * 16][0];
    unsigned short* vlds1 = &Vs[1][ws * 8][0];
    const int kswz = (lm >> 1) & 3;
    const int vswz = lm & 7;

    f32x4 o0 = {0.f, 0.f, 0.f, 0.f}, o1 = {0.f, 0.f, 0.f, 0.f}, o2 = {0.f, 0.f, 0.f, 0.f};
    const f32x4 z = {0.f, 0.f, 0.f, 0.f};

    // prefetch tile 0 into buffer 0
    if (w < 4) gload16(kg, klds0);
    else       gload16(vg, vlds0);

    #pragma unroll 2
    for (int it = 0; it < S / 64; ++it) {
        int cur = it & 1;
        __syncthreads();   // drains prefetch of tile it; orders reads of buf[1-cur] from it-1
        if (it + 1 < S / 64) {
            if (w < 4) gload16(kg + (size_t)(it + 1) * 64 * 768, cur ? klds0 : klds1);
            else       gload16(vg + (size_t)(it + 1) * 64,       cur ? vlds0 : vlds1);
        }
        #pragma unroll
        for (int half = 0; half < 2; ++half) {
            short8 kf0 = *(const short8*)&Ks[cur][half * 32 + lm][(lg ^ kswz) * 8];
            short8 kf1 = *(const short8*)&Ks[cur][half * 32 + 16 + lm][(lg ^ kswz) * 8];
            f32x4 s0 = __builtin_amdgcn_mfma_f32_16x16x32_bf16(kf0, qf, z, 0, 0, 0);
            f32x4 s1 = __builtin_amdgcn_mfma_f32_16x16x32_bf16(kf1, qf, z, 0, 0, 0);
            // lane (lm,lg): s0 = P-pre[q=lm][keys 8lg..+3], s1 = keys 8lg+4..+7
            unsigned u0[4], u1[4];
            #pragma unroll
            for (int i = 0; i < 4; ++i) {
                union { float f; unsigned u; } c0, c1;
                c0.f = __builtin_amdgcn_exp2f(s0[i]);
                c1.f = __builtin_amdgcn_exp2f(s1[i]);
                u0[i] = c0.u;   // truncate to bf16 (bias cancels num/denom)
                u1[i] = c1.u;
            }
            union { unsigned u[4]; short8 s; } pk;
            pk.u[0] = __builtin_amdgcn_perm(u0[1], u0[0], 0x07060302u);
            pk.u[1] = __builtin_amdgcn_perm(u0[3], u0[2], 0x07060302u);
            pk.u[2] = __builtin_amdgcn_perm(u1[1], u1[0], 0x07060302u);
            pk.u[3] = __builtin_amdgcn_perm(u1[3], u1[2], 0x07060302u);
            short8 pf = pk.s;   // B-operand fragment: keys 8lg..8lg+7, q=lm
            int vc = ((half * 4 + lg) ^ vswz) * 8;
            short8 va0 = *(const short8*)&Vs[cur][lm][vc];
            short8 va1 = *(const short8*)&Vs[cur][16 + lm][vc];
            short8 va2 = *(const short8*)&Ones[lm][vc];
            o0 = __builtin_amdgcn_mfma_f32_16x16x32_bf16(va0, pf, o0, 0, 0, 0);
            o1 = __builtin_amdgcn_mfma_f32_16x16x32_bf16(va1, pf, o1, 0, 0, 0);
            o2 = __builtin_amdgcn_mfma_f32_16x16x32_bf16(va2, pf, o2, 0, 0, 0);
        }
    }
    // softmax denominator for q=lm sits in lane lm (lg=0, reg 0) of o2
    float lsum = __shfl(o2[0], lm, 64);
    float inv = 1.0f / lsum;
    ushort4 r0, r1;
    r0.x = f2bf(o0[0] * inv); r0.y = f2bf(o0[1] * inv);
    r0.z = f2bf(o0[2] * inv); r0.w = f2bf(o0[3] * inv);
    r1.x = f2bf(o1[0] * inv); r1.y = f2bf(o1[1] * inv);
    r1.z = f2bf(o1[2] * inv); r1.w = f2bf(o1[3] * inv);
    unsigned short* ob = out + ((size_t)(b * S + q0 + lm)) * D + h * DH;
    *(ushort4*)(ob + lg * 4)      = r0;
    *(ushort4*)(ob + 16 + lg * 4) = r1;
}

extern "C" void kernel_launch(void* const* d_in, const int* in_sizes, int n_in,
                              void* d_out, int out_size, void* d_ws, size_t ws_size,
                              hipStream_t stream) {
    const float* x     = (const float*)d_in[0];
    const float* Wq    = (const float*)d_in[1];
    const float* Wk    = (const float*)d_in[2];
    const float* Wv    = (const float*)d_in[3];
    const float* Wo    = (const float*)d_in[4];
    const float* ln1_g = (const float*)d_in[5];
    const float* ln1_b = (const float*)d_in[6];
    const float* ln2_g = (const float*)d_in[7];
    const float* ln2_b = (const float*)d_in[8];
    const float* W2    = (const float*)d_in[9];
    const float* b2    = (const float*)d_in[10];
    const float* W3    = (const float*)d_in[11];
    const float* b3    = (const float*)d_in[12];

    char* w8 = (char*)d_ws;
    unsigned short* wqkv = (unsigned short*)(w8);             // 196608 ush
    unsigned short* wo_b = (unsigned short*)(w8 + 393216);    // 65536
    unsigned short* w2_b = (unsigned short*)(w8 + 524288);    // 262144
    unsigned short* w3_b = (unsigned short*)(w8 + 1048576);   // 262144
    float*          ct   = (float*)(w8 + 1572864);            // 65536 f32
    float*          st   = (float*)(w8 + 1835008);            // 65536 f32
    unsigned short* xn   = (unsigned short*)(w8 + 2097152);   // 2M ush (reused as yn)
    unsigned short* Cq   = (unsigned short*)(w8 + 6291456);   // 6.29M ush (QKV out)
    unsigned short* hb   = Cq;                                // MLP hidden reuses (16MB)
    unsigned short* vtb  = (unsigned short*)(w8 + 23068672);  // 2M ush
    unsigned short* ab   = (unsigned short*)(w8 + 27262976);  // 2M ush
    float*          mlpin= (float*)(w8 + 31457280);           // 2M f32
    unsigned short* yn   = xn;

    conv_all<<<3328, 256, 0, stream>>>(Wq, Wk, Wv, Wo, W2, W3, wqkv, wo_b, w2_b, w3_b, ct, st);
    ln_kernel<<<NTOK, 256, 0, stream>>>(x, ln1_g, ln1_b, xn);
    gemm_fat<<<dim3(128, 12), 256, 0, stream>>>(xn, wqkv, Cq, vtb, nullptr, nullptr, ct, st, 768, 256, 0);
    attn_kernel<<<512, 512, 0, stream>>>(Cq, vtb, ab);
    gemm_fat<<<dim3(128, 4), 256, 0, stream>>>(ab, wo_b, mlpin, nullptr, nullptr, x, nullptr, nullptr, 256, 256, 1);
    ln_kernel<<<NTOK, 256, 0, stream>>>(mlpin, ln2_g, ln2_b, yn);
    gemm_fat<<<dim3(128, 16), 256, 0, stream>>>(yn, w2_b, hb, nullptr, b2, nullptr, nullptr, nullptr, 1024, 256, 2);
    gemm_fat<<<dim3(128, 4), 256, 0, stream>>>(hb, w3_b, (float*)d_out, nullptr, b3, mlpin, nullptr, nullptr, 256, 1024, 3);
}